// Round 6
// baseline (317.541 us; speedup 1.0000x reference)
//
#include <hip/hip_runtime.h>
#include <math.h>

// S5 SSM forward — R10 resubmit (R5 was an infra failure; source audited:
// bounds/race/barrier/FIFO all clean): transpose-fused GEMMs.
// R9 post-mortem: three schedule variants all flat at MfmaUtil 17-21% ->
// schedule is not the lever at K=1024 / 2 blocks/CU. Biggest remaining cost
// is structural: two standalone transpose kernels (~96 MB each) exist only to
// feed the GEMM B-operand as N-major bf16. R10 fuses that into GEMM staging:
// B-tile reg-staged from the K-major fp32 source (u / xs) with in-register
// fp32->bf16 convert and swizzled ds_write_b64 into the SAME LDS layout the
// proven fragment reads use. A-staging keeps the R8/R9-proven gl_lds path.
// Schedule = R9's 2-phase (1 barrier + 1 vmcnt(0) per K-tile).
// BSZ=4, L=4096, H=1024, P=512.

constexpr int kB = 4, kL = 4096, kH = 1024, kP = 512;
constexpr int kM = 1024, kK = 1024, kN = 4096;

typedef short bf16x8 __attribute__((ext_vector_type(8)));
typedef float f32x4 __attribute__((ext_vector_type(4)));

// ---- ws layout (bytes), MFMA path
constexpr size_t A1H_OFF = 0;                                    // 2 MiB
constexpr size_t A2H_OFF = A1H_OFF + (size_t)kM * kK * 2;        // 2 MiB
constexpr size_t LBAR_B  = A2H_OFF + (size_t)kM * kK * 2;        // 4 KiB
constexpr size_t BU_B    = (LBAR_B + 4096 + 255) & ~(size_t)255; // 64 MiB fp32
constexpr size_t TH_B    = BU_B + (size_t)kB * kM * kN * 4;      // (unused now)
constexpr size_t MID_BYTES = TH_B + (size_t)kB * kN * kK * 2;    // ~100 MiB

// ---- bf16 helpers
__device__ __forceinline__ unsigned short f2bf(float x) {
  unsigned int u = __float_as_uint(x);
  u += 0x7fffu + ((u >> 16) & 1u);
  return (unsigned short)(u >> 16);
}

__device__ __forceinline__ void gl2lds16(const void* g, void* l) {
  __builtin_amdgcn_global_load_lds(
      (const __attribute__((address_space(1))) void*)g,
      (__attribute__((address_space(3))) void*)l, 16, 0, 0);
}

// s_waitcnt with vmcnt=N, lgkmcnt/expcnt = don't-care
template <int N>
__device__ __forceinline__ void wait_vm() {
  __builtin_amdgcn_s_waitcnt((N & 15) | ((N >> 4) << 14) | (15 << 8) | (7 << 4));
}

// ---------------------------------------------------------------- prep (merged)
// blocks 0..511: prep1 (p = bid); blocks 512..1535: prep2 (h = bid-512)
__global__ __launch_bounds__(256) void k_prep12(
    const float* __restrict__ Lre, const float* __restrict__ Lim,
    const float* __restrict__ B, const float* __restrict__ log_step,
    const float* __restrict__ C, unsigned char* __restrict__ ws) {
  int bid = blockIdx.x;
  if (bid < kP) {
    int p = bid;
    float lr = Lre[p], li = Lim[p];
    float step = expf(log_step[p]);
    float er = expf(lr * step);
    float sb, cb;
    sincosf(li * step, &sb, &cb);
    float lbr = er * cb, lbi = er * sb;
    float nr = lbr - 1.0f, ni = lbi;
    float inv = 1.0f / (lr * lr + li * li);
    float sr = (nr * lr + ni * li) * inv;
    float si = (ni * lr - nr * li) * inv;

    if (threadIdx.x == 0) ((float2*)(ws + LBAR_B))[p] = make_float2(lbr, lbi);

    unsigned short* a1h = (unsigned short*)(ws + A1H_OFF);
    const float* Brow = B + (size_t)p * kH * 2;
    for (int h = threadIdx.x; h < kH; h += 256) {
      float br = Brow[2 * h], bi = Brow[2 * h + 1];
      a1h[(size_t)p * kK + h] = f2bf(sr * br - si * bi);
      a1h[(size_t)(kP + p) * kK + h] = f2bf(sr * bi + si * br);
    }
  } else {
    int h = bid - kP;
    unsigned short* a2h = (unsigned short*)(ws + A2H_OFF);
    for (int k = threadIdx.x; k < kK; k += 256) {
      float v = (k < kP) ? 2.f * C[((size_t)h * kP + k) * 2]
                         : -2.f * C[((size_t)h * kP + (k - kP)) * 2 + 1];
      a2h[(size_t)h * kK + k] = f2bf(v);
    }
  }
}

// ================================================================ fused GEMM
// Tile 128(M) x 256(N), BK=32, 512 threads = 8 waves (2M x 4N), per-wave 64x64.
// out[b][m][n] = sum_k A[m][k] * S[b][k][n]  (S is K-major fp32: u or xs).
// LDS 48 KiB = 2 bufs x 24 KiB (A 8KB + B 16KB), 16rowx32k subtiles (1024B)
// with st_16x32 swizzle (row&8 -> byte^32).
//  A: bf16 [m][k] staged by gl_lds, LINEAR dest + inverse-swz global src
//     (byte-identical decode to R8/R9, HW-proven 0 conflicts).
//  B: fp32 [k][n] reg-staged: thread (kg=tid&7, ng=tid>>3) loads 4x float4
//     rows k0=kg*4..+3 cols n=ng*4..+3, converts, ds_write_b64 per n-row at
//     swizzled (n, k0) — same layout the fragment reads expect.
// Schedule per K-tile: issue next-tile loads -> 8 ds_read frags -> lgkmcnt(0)
// -> setprio(1) 16 MFMA setprio(0) -> vmcnt(0) -> cvt+ds_write -> lgkmcnt(0)
// -> s_barrier.

__device__ __forceinline__ int stage_src_off32(int Dp) {
  int Ds = Dp ^ (((Dp >> 9) & 1) << 5);  // involution
  int s = Ds >> 10, d = Ds & 1023;       // subtile (row-block), within-subtile
  int row = (s << 4) + (d >> 6);         // 0..127
  int kk = (d & 63) >> 1;                // 0..31 (multiple of 8)
  return row * kK + kk;
}

struct f4x4 { float4 v[4]; };

#define BAR __builtin_amdgcn_s_barrier()
#define LGKM0                                           \
  do {                                                  \
    asm volatile("s_waitcnt lgkmcnt(0)" ::: "memory");  \
    __builtin_amdgcn_sched_barrier(0);                  \
  } while (0)

template <bool EPI>
__global__ __launch_bounds__(512, 4) void k_gemmf(
    const unsigned short* __restrict__ Ah, const float* __restrict__ S,
    float* __restrict__ out, const float* __restrict__ u,
    const float* __restrict__ D) {
  __shared__ __align__(16) unsigned char lds[49152];
  constexpr int BUF = 24576;
  constexpr int NKT = kK / 32;  // 32 K-tiles

  int b = blockIdx.z;
  int m0 = blockIdx.y * 128, n0 = blockIdx.x * 256;
  int tid = threadIdx.x, w = tid >> 6;
  int q = (tid >> 4) & 3, r = tid & 15;
  int wm = (w >> 2) * 64, wn = (w & 3) * 64;
  int wmrb = (w >> 2) * 4, wnrb = (w & 3) * 4;
  int lane_off = (r * 64 + q * 16) ^ ((r & 8) << 2);  // st_16x32 read swizzle

  int d0 = tid << 4;
  int rowk = stage_src_off32(d0);  // A gl_lds source decode (rows = m)

  const unsigned short* pA = Ah + (size_t)m0 * kK;
  const float* pS = S + (size_t)b * ((size_t)kK * kN) + n0;  // [k][n], k-major

  // B reg-staging thread map
  int kg = tid & 7, ng = tid >> 3;  // k0 = kg*4, n = ng*4 + j
  int wadr[4];
#pragma unroll
  for (int j = 0; j < 4; j++) {
    int n = ng * 4 + j;
    int a0 = ((n >> 4) << 10) + (n & 15) * 64 + kg * 8;
    wadr[j] = a0 ^ ((n & 8) ? 32 : 0);
  }
  const float* pSb = pS + (size_t)(kg * 4) * kN + ng * 4;

  f32x4 acc[4][4] = {};

  // ---- helpers (inlined via lambdas kept as macros for scheduling clarity)
#define BLOAD(T, KT)                                                    \
  do {                                                                  \
    const float* bs_ = pSb + (size_t)(KT) * 32 * kN;                    \
    _Pragma("unroll")                                                   \
    for (int i_ = 0; i_ < 4; i_++)                                      \
      (T).v[i_] = *(const float4*)(bs_ + (size_t)i_ * kN);              \
  } while (0)

#define BWRITE(T, LB)                                                   \
  do {                                                                  \
    const float* f0_ = (const float*)&(T).v[0];                         \
    const float* f1_ = (const float*)&(T).v[1];                         \
    const float* f2_ = (const float*)&(T).v[2];                         \
    const float* f3_ = (const float*)&(T).v[3];                         \
    _Pragma("unroll")                                                   \
    for (int j_ = 0; j_ < 4; j_++) {                                    \
      unsigned int lo_ = ((unsigned int)f2bf(f1_[j_]) << 16) | f2bf(f0_[j_]); \
      unsigned int hi_ = ((unsigned int)f2bf(f3_[j_]) << 16) | f2bf(f2_[j_]); \
      *(uint2*)(lds + (LB) + 8192 + wadr[j_]) = make_uint2(lo_, hi_);   \
    }                                                                   \
  } while (0)

  // prologue: fill buf0 with kt=0
  {
    f4x4 t;
    BLOAD(t, 0);
    gl2lds16(pA + rowk, lds + d0);  // A kt0 -> buf0
    wait_vm<0>();
    BWRITE(t, 0);
    LGKM0;
  }
  BAR;

  for (int kt = 0; kt < NKT; ++kt) {
    int cur = (kt & 1) ? BUF : 0;
    int nxt = cur ^ BUF;
    bool pf = (kt + 1 < NKT);
    f4x4 t;
    if (pf) {
      BLOAD(t, kt + 1);
      gl2lds16(pA + (kt + 1) * 32 + rowk, lds + nxt + d0);
    }
    bf16x8 a[4], bb[4];
#pragma unroll
    for (int mi = 0; mi < 4; mi++)
      a[mi] = *(const bf16x8*)(lds + cur + ((wmrb + mi) << 10) + lane_off);
#pragma unroll
    for (int nj = 0; nj < 4; nj++)
      bb[nj] = *(const bf16x8*)(lds + cur + 8192 + ((wnrb + nj) << 10) + lane_off);
    LGKM0;
    __builtin_amdgcn_s_setprio(1);
#pragma unroll
    for (int mi = 0; mi < 4; mi++)
#pragma unroll
      for (int nj = 0; nj < 4; nj++)
        acc[mi][nj] = __builtin_amdgcn_mfma_f32_16x16x32_bf16(
            a[mi], bb[nj], acc[mi][nj], 0, 0, 0);
    __builtin_amdgcn_s_setprio(0);
    wait_vm<0>();  // A gl_lds (and B loads) landed
    if (pf) {
      BWRITE(t, nxt);
      LGKM0;  // ds_writes complete before barrier
    }
    BAR;
  }
#undef BLOAD
#undef BWRITE

  // C/D layout: col = r, row = q*4 + reg   [R8/R9-proven]
#pragma unroll
  for (int mi = 0; mi < 4; mi++) {
#pragma unroll
    for (int reg = 0; reg < 4; reg++) {
      int row = m0 + wm + mi * 16 + q * 4 + reg;
      float dv = EPI ? D[row] : 0.f;
#pragma unroll
      for (int ni = 0; ni < 4; ni++) {
        int col = n0 + wn + ni * 16 + r;
        size_t o = ((size_t)b * kM + row) * (size_t)kN + col;
        float v = acc[mi][ni][reg];
        if (EPI) {
          float y = v + dv * u[o];
          v = 0.5f * y * (1.f + erff(y * 0.70710678118654752f));
        }
        out[o] = v;
      }
    }
  }
}

// ---------------------------------------------------------------- scan (fp32 planar, in-place)
// [replay-proven]
__global__ __launch_bounds__(256) void k_scan(float* __restrict__ bu,
                                              const float2* __restrict__ lbar) {
  int p = blockIdx.x & (kP - 1);
  int b = blockIdx.x >> 9;
  int tid = threadIdx.x, lane = tid & 63, w = tid >> 6;
  float2 lam = lbar[p];
  float* sre = bu + ((size_t)b * kM + p) * (size_t)kN;
  float* sim = sre + (size_t)kP * kN;

  float vr[16], vi[16];
  {
    const float4* pr = (const float4*)(sre + tid * 16);
    const float4* pi = (const float4*)(sim + tid * 16);
#pragma unroll
    for (int i = 0; i < 4; i++) {
      float4 a = pr[i], c = pi[i];
      vr[4 * i] = a.x; vr[4 * i + 1] = a.y; vr[4 * i + 2] = a.z; vr[4 * i + 3] = a.w;
      vi[4 * i] = c.x; vi[4 * i + 1] = c.y; vi[4 * i + 2] = c.z; vi[4 * i + 3] = c.w;
    }
  }

  float xr = 0.f, xi = 0.f;
#pragma unroll
  for (int i = 0; i < 16; i++) {
    float nr2 = fmaf(lam.x, xr, fmaf(-lam.y, xi, vr[i]));
    float ni2 = fmaf(lam.x, xi, fmaf(lam.y, xr, vi[i]));
    xr = nr2; xi = ni2;
  }

  float Ar = lam.x, Ai = lam.y;
#pragma unroll
  for (int s = 0; s < 4; s++) {
    float tr = Ar * Ar - Ai * Ai, ti = 2.f * Ar * Ai;
    Ar = tr; Ai = ti;
  }
  float br = xr, bi = xi;

  for (int off = 1; off < 64; off <<= 1) {
    float pAr = __shfl_up(Ar, off), pAi = __shfl_up(Ai, off);
    float pbr = __shfl_up(br, off), pbi = __shfl_up(bi, off);
    if (lane >= off) {
      float nAr = Ar * pAr - Ai * pAi;
      float nAi = Ar * pAi + Ai * pAr;
      float nbr = Ar * pbr - Ai * pbi + br;
      float nbi = Ar * pbi + Ai * pbr + bi;
      Ar = nAr; Ai = nAi; br = nbr; bi = nbi;
    }
  }

  __shared__ float4 wtot[4];
  if (lane == 63) wtot[w] = make_float4(Ar, Ai, br, bi);
  __syncthreads();

  float eAr = __shfl_up(Ar, 1), eAi = __shfl_up(Ai, 1);
  float ebr = __shfl_up(br, 1), ebi = __shfl_up(bi, 1);
  if (lane == 0) { eAr = 1.f; eAi = 0.f; ebr = 0.f; ebi = 0.f; }

  float pAr = 1.f, pAi = 0.f, pbr = 0.f, pbi = 0.f;
  for (int j = 0; j < w; j++) {
    float4 t = wtot[j];
    float nAr = t.x * pAr - t.y * pAi;
    float nAi = t.x * pAi + t.y * pAr;
    float nbr = t.x * pbr - t.y * pbi + t.z;
    float nbi = t.x * pbi + t.y * pbr + t.w;
    pAr = nAr; pAi = nAi; pbr = nbr; pbi = nbi;
  }

  float initr = eAr * pbr - eAi * pbi + ebr;
  float initi = eAr * pbi + eAi * pbr + ebi;

  xr = initr; xi = initi;
  float4* qr = (float4*)(sre + tid * 16);
  float4* qi = (float4*)(sim + tid * 16);
#pragma unroll
  for (int i = 0; i < 4; i++) {
    float rr[4], ii[4];
#pragma unroll
    for (int j = 0; j < 4; j++) {
      float nr2 = fmaf(lam.x, xr, fmaf(-lam.y, xi, vr[4 * i + j]));
      float ni2 = fmaf(lam.x, xi, fmaf(lam.y, xr, vi[4 * i + j]));
      xr = nr2; xi = ni2; rr[j] = nr2; ii[j] = ni2;
    }
    qr[i] = make_float4(rr[0], rr[1], rr[2], rr[3]);
    qi[i] = make_float4(ii[0], ii[1], ii[2], ii[3]);
  }
}

// ================================================================ fp32 fallback
constexpr size_t OBBAR = 0;
constexpr size_t OLBAR = (size_t)kP * kH;
constexpr size_t OBU = OLBAR + 1024;

__global__ __launch_bounds__(256) void k_precomputeF(
    const float* __restrict__ Lre, const float* __restrict__ Lim,
    const float* __restrict__ B, const float* __restrict__ log_step,
    float2* __restrict__ ws) {
  int p = blockIdx.x;
  float lr = Lre[p], li = Lim[p];
  float step = expf(log_step[p]);
  float er = expf(lr * step);
  float sb, cb;
  sincosf(li * step, &sb, &cb);
  float lbr = er * cb, lbi = er * sb;
  float nr = lbr - 1.0f, ni = lbi;
  float inv = 1.0f / (lr * lr + li * li);
  float sr = (nr * lr + ni * li) * inv;
  float si = (ni * lr - nr * li) * inv;
  if (threadIdx.x == 0) ws[OLBAR + p] = make_float2(lbr, lbi);
  float2* Bbar = ws + OBBAR;
  const float* Brow = B + (size_t)p * kH * 2;
  for (int h = threadIdx.x; h < kH; h += 256) {
    float br = Brow[2 * h], bi = Brow[2 * h + 1];
    Bbar[(size_t)p * kH + h] = make_float2(sr * br - si * bi, sr * bi + si * br);
  }
}

__global__ __launch_bounds__(256) void k_gemm1F(
    const float2* __restrict__ ws_bbar, const float* __restrict__ u,
    float2* __restrict__ Bu) {
  __shared__ float2 As[16][64];
  __shared__ float Bs[16][64];
  int b = blockIdx.z, m0 = blockIdx.y * 64, n0 = blockIdx.x * 64;
  int tid = threadIdx.x, tn = tid & 15, tm = tid >> 4;
  const float* uB = u + (size_t)b * kH * kL;
  float2 acc[4][4];
#pragma unroll
  for (int i = 0; i < 4; i++)
#pragma unroll
    for (int j = 0; j < 4; j++) acc[i][j] = make_float2(0.f, 0.f);
  int ar = tid >> 2, ac = (tid & 3) * 4, bk = tid >> 4, bc = (tid & 15) * 4;
  for (int k0 = 0; k0 < kH; k0 += 16) {
    const float4* src = (const float4*)(ws_bbar + (size_t)(m0 + ar) * kH + k0 + ac);
    float4 v01 = src[0], v23 = src[1];
    As[ac + 0][ar] = make_float2(v01.x, v01.y);
    As[ac + 1][ar] = make_float2(v01.z, v01.w);
    As[ac + 2][ar] = make_float2(v23.x, v23.y);
    As[ac + 3][ar] = make_float2(v23.z, v23.w);
    float4 v = *(const float4*)(uB + (size_t)(k0 + bk) * kL + n0 + bc);
    *(float4*)&Bs[bk][bc] = v;
    __syncthreads();
#pragma unroll
    for (int kk = 0; kk < 16; ++kk) {
      const float4* arow = (const float4*)&As[kk][0];
      float4 a01 = arow[tm * 2 + 0], a23 = arow[tm * 2 + 1];
      float2 a[4] = {make_float2(a01.x, a01.y), make_float2(a01.z, a01.w),
                     make_float2(a23.x, a23.y), make_float2(a23.z, a23.w)};
      float4 bv = ((const float4*)&Bs[kk][0])[tn];
      float bbv[4] = {bv.x, bv.y, bv.z, bv.w};
#pragma unroll
      for (int mi = 0; mi < 4; mi++)
#pragma unroll
        for (int ni = 0; ni < 4; ni++) {
          acc[mi][ni].x = fmaf(a[mi].x, bbv[ni], acc[mi][ni].x);
          acc[mi][ni].y = fmaf(a[mi].y, bbv[ni], acc[mi][ni].y);
        }
    }
    __syncthreads();
  }
  float2* BuB = Bu + (size_t)b * kP * kL;
#pragma unroll
  for (int mi = 0; mi < 4; mi++) {
    int row = m0 + tm * 4 + mi;
    float2* dst = BuB + (size_t)row * kL + n0 + tn * 4;
    ((float4*)dst)[0] = make_float4(acc[mi][0].x, acc[mi][0].y, acc[mi][1].x, acc[mi][1].y);
    ((float4*)dst)[1] = make_float4(acc[mi][2].x, acc[mi][2].y, acc[mi][3].x, acc[mi][3].y);
  }
}

__global__ __launch_bounds__(256) void k_scanF(float2* __restrict__ Bu,
                                               const float2* __restrict__ Lbar) {
  int p = blockIdx.x & (kP - 1);
  int b = blockIdx.x >> 9;
  int tid = threadIdx.x, lane = tid & 63, w = tid >> 6;
  float2 lam = Lbar[p];
  float2* seq = Bu + ((size_t)b * kP + p) * kL;
  float2 v[16];
  const float4* src = (const float4*)(seq + tid * 16);
#pragma unroll
  for (int i = 0; i < 8; i++) {
    float4 t = src[i];
    v[2 * i] = make_float2(t.x, t.y);
    v[2 * i + 1] = make_float2(t.z, t.w);
  }
  float xr = 0.f, xi = 0.f;
#pragma unroll
  for (int i = 0; i < 16; i++) {
    float nr2 = fmaf(lam.x, xr, fmaf(-lam.y, xi, v[i].x));
    float ni2 = fmaf(lam.x, xi, fmaf(lam.y, xr, v[i].y));
    xr = nr2; xi = ni2;
  }
  float Ar = lam.x, Ai = lam.y;
#pragma unroll
  for (int s = 0; s < 4; s++) {
    float tr = Ar * Ar - Ai * Ai, ti = 2.f * Ar * Ai;
    Ar = tr; Ai = ti;
  }
  float br = xr, bi = xi;
  for (int off = 1; off < 64; off <<= 1) {
    float pAr = __shfl_up(Ar, off), pAi = __shfl_up(Ai, off);
    float pbr = __shfl_up(br, off), pbi = __shfl_up(bi, off);
    if (lane >= off) {
      float nAr = Ar * pAr - Ai * pAi, nAi = Ar * pAi + Ai * pAr;
      float nbr = Ar * pbr - Ai * pbi + br, nbi = Ar * pbi + Ai * pbr + bi;
      Ar = nAr; Ai = nAi; br = nbr; bi = nbi;
    }
  }
  __shared__ float4 wtot[4];
  if (lane == 63) wtot[w] = make_float4(Ar, Ai, br, bi);
  __syncthreads();
  float eAr = __shfl_up(Ar, 1), eAi = __shfl_up(Ai, 1);
  float ebr = __shfl_up(br, 1), ebi = __shfl_up(bi, 1);
  if (lane == 0) { eAr = 1.f; eAi = 0.f; ebr = 0.f; ebi = 0.f; }
  float pAr = 1.f, pAi = 0.f, pbr = 0.f, pbi = 0.f;
  for (int j = 0; j < w; j++) {
    float4 t = wtot[j];
    float nAr = t.x * pAr - t.y * pAi, nAi = t.x * pAi + t.y * pAr;
    float nbr = t.x * pbr - t.y * pbi + t.z, nbi = t.x * pbi + t.y * pbr + t.w;
    pAr = nAr; pAi = nAi; pbr = nbr; pbi = nbi;
  }
  float initr = eAr * pbr - eAi * pbi + ebr;
  float initi = eAr * pbi + eAi * pbr + ebi;
  xr = initr; xi = initi;
  float4* dst = (float4*)(seq + tid * 16);
#pragma unroll
  for (int i = 0; i < 8; i++) {
    float nr0 = fmaf(lam.x, xr, fmaf(-lam.y, xi, v[2 * i].x));
    float ni0 = fmaf(lam.x, xi, fmaf(lam.y, xr, v[2 * i].y));
    float nr1 = fmaf(lam.x, nr0, fmaf(-lam.y, ni0, v[2 * i + 1].x));
    float ni1 = fmaf(lam.x, ni0, fmaf(lam.y, nr0, v[2 * i + 1].y));
    dst[i] = make_float4(nr0, ni0, nr1, ni1);
    xr = nr1; xi = ni1;
  }
}

__global__ __launch_bounds__(256) void k_gemm2F(
    const float2* __restrict__ C, const float2* __restrict__ X,
    const float* __restrict__ u, const float* __restrict__ D,
    float* __restrict__ out) {
  __shared__ float2 As[16][64];
  __shared__ float2 Bs[16][64];
  int b = blockIdx.z, m0 = blockIdx.y * 64, n0 = blockIdx.x * 64;
  int tid = threadIdx.x, tn = tid & 15, tm = tid >> 4;
  const float2* Xb = X + (size_t)b * kP * kL;
  float acc[4][4];
#pragma unroll
  for (int i = 0; i < 4; i++)
#pragma unroll
    for (int j = 0; j < 4; j++) acc[i][j] = 0.f;
  int ar = tid >> 2, ac = (tid & 3) * 4, bk = tid >> 4, bc = (tid & 15) * 4;
  for (int k0 = 0; k0 < kP; k0 += 16) {
    const float4* src = (const float4*)(C + (size_t)(m0 + ar) * kP + k0 + ac);
    float4 v01 = src[0], v23 = src[1];
    As[ac + 0][ar] = make_float2(v01.x, v01.y);
    As[ac + 1][ar] = make_float2(v01.z, v01.w);
    As[ac + 2][ar] = make_float2(v23.x, v23.y);
    As[ac + 3][ar] = make_float2(v23.z, v23.w);
    const float4* srcb = (const float4*)(Xb + (size_t)(k0 + bk) * kL + n0 + bc);
    ((float4*)&Bs[bk][bc])[0] = srcb[0];
    ((float4*)&Bs[bk][bc])[1] = srcb[1];
    __syncthreads();
#pragma unroll
    for (int kk = 0; kk < 16; ++kk) {
      const float4* arow = (const float4*)&As[kk][0];
      float4 a01 = arow[tm * 2 + 0], a23 = arow[tm * 2 + 1];
      float2 a[4] = {make_float2(a01.x, a01.y), make_float2(a01.z, a01.w),
                     make_float2(a23.x, a23.y), make_float2(a23.z, a23.w)};
      const float4* brow = (const float4*)&Bs[kk][0];
      float4 b01 = brow[tn * 2 + 0], b23 = brow[tn * 2 + 1];
      float2 bbv[4] = {make_float2(b01.x, b01.y), make_float2(b01.z, b01.w),
                       make_float2(b23.x, b23.y), make_float2(b23.z, b23.w)};
#pragma unroll
      for (int mi = 0; mi < 4; mi++)
#pragma unroll
        for (int ni = 0; ni < 4; ni++) {
          acc[mi][ni] = fmaf(a[mi].x, bbv[ni].x, acc[mi][ni]);
          acc[mi][ni] = fmaf(-a[mi].y, bbv[ni].y, acc[mi][ni]);
        }
    }
    __syncthreads();
  }
#pragma unroll
  for (int mi = 0; mi < 4; mi++) {
    int h = m0 + tm * 4 + mi;
    float d = D[h];
    const float* urow = u + ((size_t)b * kH + h) * kL + n0 + tn * 4;
    float4 uv = *(const float4*)urow;
    float uu[4] = {uv.x, uv.y, uv.z, uv.w};
    float res[4];
#pragma unroll
    for (int ni = 0; ni < 4; ni++) {
      float y = 2.f * acc[mi][ni] + d * uu[ni];
      res[ni] = 0.5f * y * (1.f + erff(y * 0.70710678118654752f));
    }
    float* orow = out + ((size_t)b * kH + h) * kL + n0 + tn * 4;
    *(float4*)orow = make_float4(res[0], res[1], res[2], res[3]);
  }
}

// ---------------------------------------------------------------- launch
extern "C" void kernel_launch(void* const* d_in, const int* in_sizes, int n_in,
                              void* d_out, int out_size, void* d_ws, size_t ws_size,
                              hipStream_t stream) {
  const float* input_sequence = (const float*)d_in[0];
  const float* Lambda_re = (const float*)d_in[2];
  const float* Lambda_im = (const float*)d_in[3];
  const float* B = (const float*)d_in[4];
  const float* C = (const float*)d_in[5];
  const float* D = (const float*)d_in[6];
  const float* log_step = (const float*)d_in[7];
  float* out = (float*)d_out;

  if (ws_size >= MID_BYTES) {
    unsigned char* ws = (unsigned char*)d_ws;
    unsigned short* a1h = (unsigned short*)(ws + A1H_OFF);
    unsigned short* a2h = (unsigned short*)(ws + A2H_OFF);
    float2* lbar = (float2*)(ws + LBAR_B);
    float* bu = (float*)(ws + BU_B);

    k_prep12<<<dim3(kP + kH), 256, 0, stream>>>(Lambda_re, Lambda_im, B,
                                                log_step, C, ws);

    dim3 ggrid(kN / 256, kM / 128, kB);  // 16 x 8 x 4 = 512 blocks

    // GEMM1: A1[m][h] x u[b][h][l] -> bu[b][m][l]  (B-operand fused-transposed)
    k_gemmf<false><<<ggrid, 512, 0, stream>>>(a1h, input_sequence, bu,
                                              nullptr, nullptr);
    k_scan<<<dim3(kB * kP), 256, 0, stream>>>(bu, lbar);
    // GEMM2: A2[h][m] x xs[b][m][l] -> out[b][h][l], + D*u + GeLU
    k_gemmf<true><<<ggrid, 512, 0, stream>>>(a2h, bu, out, input_sequence, D);
  } else {
    // fp32 fallback (round-1 path)
    float2* ws = (float2*)d_ws;
    float2* Bbar = ws + OBBAR;
    float2* Lbar = ws + OLBAR;
    float2* Bu = ws + OBU;
    k_precomputeF<<<dim3(kP), 256, 0, stream>>>(Lambda_re, Lambda_im, B, log_step, ws);
    k_gemm1F<<<dim3(kL / 64, kP / 64, kB), 256, 0, stream>>>(Bbar, input_sequence, Bu);
    k_scanF<<<dim3(kB * kP), 256, 0, stream>>>(Bu, Lbar);
    k_gemm2F<<<dim3(kL / 64, kH / 64, kB), 256, 0, stream>>>(
        (const float2*)C, (const float2*)Bu, input_sequence, D, out);
  }
}

// Round 7
// 285.527 us; speedup vs baseline: 1.1121x; 1.1121x over previous
//
#include <hip/hip_runtime.h>
#include <math.h>

// S5 SSM forward — R11: R9 structure + 3-buffer ring with counted vmcnt.
// R10 post-mortem: fused B-transpose put cvt+ds_write in the serial critical
// section -> regressed (105us vs 65). Reverted. R9's binding cost per K-tile
// was the vmcnt(0) drain (~600-900cy gl_lds round trip). R11 deepens prefetch:
// 3 x 24KiB LDS buffers (72KiB, still 2 blocks/CU), stage tile kt+2 each iter,
// steady-state wait_vm<6> (tile kt's 3 loads retired; kt+1/kt+2 stay in
// flight). Two barriers/iter (overwrite hazard: STG at iter kt+1 targets the
// buffer compute(kt) read); both are cheap when no wave is drained.
// Transposes / scan / prep unchanged (replay-proven).
// BSZ=4, L=4096, H=1024, P=512.

constexpr int kB = 4, kL = 4096, kH = 1024, kP = 512;
constexpr int kM = 1024, kK = 1024, kN = 4096;

typedef short bf16x8 __attribute__((ext_vector_type(8)));
typedef float f32x4 __attribute__((ext_vector_type(4)));

// ---- ws layout (bytes), MFMA path
constexpr size_t A1H_OFF = 0;                                    // 2 MiB
constexpr size_t A2H_OFF = A1H_OFF + (size_t)kM * kK * 2;        // 2 MiB
constexpr size_t LBAR_B  = A2H_OFF + (size_t)kM * kK * 2;        // 4 KiB
constexpr size_t BU_B    = (LBAR_B + 4096 + 255) & ~(size_t)255; // 64 MiB fp32
constexpr size_t TH_B    = BU_B + (size_t)kB * kM * kN * 4;      // 32 MiB bf16
constexpr size_t MID_BYTES = TH_B + (size_t)kB * kN * kK * 2;    // ~100 MiB

// ---- bf16 helpers
__device__ __forceinline__ unsigned short f2bf(float x) {
  unsigned int u = __float_as_uint(x);
  u += 0x7fffu + ((u >> 16) & 1u);
  return (unsigned short)(u >> 16);
}

__device__ __forceinline__ void gl2lds16(const void* g, void* l) {
  __builtin_amdgcn_global_load_lds(
      (const __attribute__((address_space(1))) void*)g,
      (__attribute__((address_space(3))) void*)l, 16, 0, 0);
}

// s_waitcnt with vmcnt=N, lgkmcnt/expcnt = don't-care
template <int N>
__device__ __forceinline__ void wait_vm() {
  __builtin_amdgcn_s_waitcnt((N & 15) | ((N >> 4) << 14) | (15 << 8) | (7 << 4));
}

// ---------------------------------------------------------------- prep (merged)
// blocks 0..511: prep1 (p = bid); blocks 512..1535: prep2 (h = bid-512)
__global__ __launch_bounds__(256) void k_prep12(
    const float* __restrict__ Lre, const float* __restrict__ Lim,
    const float* __restrict__ B, const float* __restrict__ log_step,
    const float* __restrict__ C, unsigned char* __restrict__ ws) {
  int bid = blockIdx.x;
  if (bid < kP) {
    int p = bid;
    float lr = Lre[p], li = Lim[p];
    float step = expf(log_step[p]);
    float er = expf(lr * step);
    float sb, cb;
    sincosf(li * step, &sb, &cb);
    float lbr = er * cb, lbi = er * sb;
    float nr = lbr - 1.0f, ni = lbi;
    float inv = 1.0f / (lr * lr + li * li);
    float sr = (nr * lr + ni * li) * inv;
    float si = (ni * lr - nr * li) * inv;

    if (threadIdx.x == 0) ((float2*)(ws + LBAR_B))[p] = make_float2(lbr, lbi);

    unsigned short* a1h = (unsigned short*)(ws + A1H_OFF);
    const float* Brow = B + (size_t)p * kH * 2;
    for (int h = threadIdx.x; h < kH; h += 256) {
      float br = Brow[2 * h], bi = Brow[2 * h + 1];
      a1h[(size_t)p * kK + h] = f2bf(sr * br - si * bi);
      a1h[(size_t)(kP + p) * kK + h] = f2bf(sr * bi + si * br);
    }
  } else {
    int h = bid - kP;
    unsigned short* a2h = (unsigned short*)(ws + A2H_OFF);
    for (int k = threadIdx.x; k < kK; k += 256) {
      float v = (k < kP) ? 2.f * C[((size_t)h * kP + k) * 2]
                         : -2.f * C[((size_t)h * kP + (k - kP)) * 2 + 1];
      a2h[(size_t)h * kK + k] = f2bf(v);
    }
  }
}

// ---------------------------------------------------------------- transpose (fp32 -> bf16T)
// in: fp32 [b][1024][4096] -> out: bf16 [b][4096][1024]   [replay-proven]
__global__ __launch_bounds__(256) void k_transpose(
    const float* __restrict__ in, unsigned short* __restrict__ oh) {
  __shared__ float t[64][65];
  int b = blockIdx.z;
  int r0 = blockIdx.y * 64;
  int c0 = blockIdx.x * 64;
  int tid = threadIdx.x;
  const float* src = in + ((size_t)b * 1024 + r0) * 4096 + c0;
  int cc = (tid & 15) * 4, rr = tid >> 4;
#pragma unroll
  for (int i = 0; i < 4; i++) {
    float4 v = *(const float4*)(src + (size_t)(rr + i * 16) * 4096 + cc);
    t[rr + i * 16][cc + 0] = v.x;
    t[rr + i * 16][cc + 1] = v.y;
    t[rr + i * 16][cc + 2] = v.z;
    t[rr + i * 16][cc + 3] = v.w;
  }
  __syncthreads();
  int oc = tid >> 2;
  int og = (tid & 3) * 2;
#pragma unroll
  for (int i = 0; i < 2; i++) {
    int g = og + i;
    unsigned short hv[8];
#pragma unroll
    for (int j = 0; j < 8; j++) hv[j] = f2bf(t[g * 8 + j][oc]);
    size_t ob = ((size_t)b * 4096 + c0 + oc) * 1024 + r0 + g * 8;
    *(uint4*)(oh + ob) = *(uint4*)hv;
  }
}

// ================================================================ 3-buffer GEMM
// Tile 128(M) x 256(N), BK=32, 512 threads = 8 waves (2M x 4N), per-wave 64x64.
// LDS 72 KiB = 3 bufs x 24 KiB (A 8KB + B 16KB), 16rowx32k subtiles (1024B)
// with st_16x32 swizzle; staged via gl_lds LINEAR dest + inv-swz global src
// (byte-identical decode to R8/R9, HW-proven 0 conflicts).
// Ring schedule (prefetch distance 2, 3 gl_lds per tile per thread):
//   prologue: STG(t0,b0) STG(t1,b1); wait_vm<3>; BAR
//   iter kt (0..29): STG(kt+2 -> buf[(kt+2)%3]); wait_vm<6>; BAR;
//                    compute(buf[kt%3]); BAR
//   tail: wait_vm<3>; BAR; compute(b0 = t30); wait_vm<0>; BAR; compute(b1 = t31)

__device__ __forceinline__ int stage_src_off32(int Dp) {
  int Ds = Dp ^ (((Dp >> 9) & 1) << 5);  // involution
  int s = Ds >> 10, d = Ds & 1023;       // subtile (row-block), within-subtile
  int row = (s << 4) + (d >> 6);         // 0..127
  int kk = (d & 63) >> 1;                // 0..31 (multiple of 8)
  return row * kK + kk;
}

#define BAR __builtin_amdgcn_s_barrier()
#define LGKM0                                           \
  do {                                                  \
    asm volatile("s_waitcnt lgkmcnt(0)" ::: "memory");  \
    __builtin_amdgcn_sched_barrier(0);                  \
  } while (0)

template <bool EPI>
__global__ __launch_bounds__(512, 4) void k_gemm3b(
    const unsigned short* __restrict__ Ah, const unsigned short* __restrict__ Bh,
    float* __restrict__ out, const float* __restrict__ u,
    const float* __restrict__ D) {
  __shared__ __align__(16) unsigned char lds[73728];
  constexpr int BSZ = 24576;
  constexpr int NKT = kK / 32;  // 32 K-tiles

  int b = blockIdx.z;
  int m0 = blockIdx.y * 128, n0 = blockIdx.x * 256;
  int tid = threadIdx.x, w = tid >> 6;
  int q = (tid >> 4) & 3, r = tid & 15;
  int wm = (w >> 2) * 64, wn = (w & 3) * 64;
  int wmrb = (w >> 2) * 4, wnrb = (w & 3) * 4;
  int lane_off = (r * 64 + q * 16) ^ ((r & 8) << 2);  // st_16x32 read swizzle

  int d0 = tid << 4;
  int rowk = stage_src_off32(d0);  // same decode for A piece and each B half

  const unsigned short* pA = Ah + (size_t)m0 * kK;
  const unsigned short* pB = Bh + (size_t)b * kN * kK + (size_t)n0 * kK;

  f32x4 acc[4][4] = {};

  // one K-tile stage: A 8KB + B 16KB (two halves) = 3 gl_lds per thread
#define STG(KT, LB)                                                       \
  do {                                                                    \
    gl2lds16(pA + (KT) * 32 + rowk, lds + (LB) + d0);                     \
    gl2lds16(pB + (KT) * 32 + rowk, lds + (LB) + 8192 + d0);              \
    gl2lds16(pB + (size_t)128 * kK + (KT) * 32 + rowk,                    \
             lds + (LB) + 16384 + d0);                                    \
  } while (0)

  // one K-tile compute: 4 A-frags + 4 B-frags -> 16 MFMA into acc
#define COMPUTE(LB)                                                       \
  do {                                                                    \
    bf16x8 a[4], bb[4];                                                   \
    _Pragma("unroll")                                                     \
    for (int mi = 0; mi < 4; mi++)                                        \
      a[mi] = *(const bf16x8*)(lds + (LB) + ((wmrb + mi) << 10) + lane_off); \
    _Pragma("unroll")                                                     \
    for (int nj = 0; nj < 4; nj++)                                        \
      bb[nj] = *(const bf16x8*)(lds + (LB) + 8192 +                       \
                                ((wnrb + nj) << 10) + lane_off);          \
    LGKM0;                                                                \
    __builtin_amdgcn_s_setprio(1);                                        \
    _Pragma("unroll")                                                     \
    for (int mi = 0; mi < 4; mi++)                                        \
      _Pragma("unroll")                                                   \
      for (int nj = 0; nj < 4; nj++)                                      \
        acc[mi][nj] = __builtin_amdgcn_mfma_f32_16x16x32_bf16(            \
            a[mi], bb[nj], acc[mi][nj], 0, 0, 0);                         \
    __builtin_amdgcn_s_setprio(0);                                        \
  } while (0)

  // prologue: tiles 0,1 into buf0,buf1; wait tile0 (retire 3 of 6)
  STG(0, 0);
  STG(1, BSZ);
  wait_vm<3>();
  BAR;

  int sb = 2 * BSZ;  // stage target: buf[(kt+2)%3], iter0 -> buf2
  int cb = 0;        // compute buf: buf[kt%3]
  for (int kt = 0; kt < NKT - 2; ++kt) {
    STG(kt + 2, sb);
    // FIFO: outstanding {kt,kt+1,kt+2}=9 -> retire tile kt's 3, keep 6 in flight
    wait_vm<6>();
    BAR;  // all waves' tile-kt loads landed & visible
    COMPUTE(cb);
    BAR;  // all reads of buf[kt%3] done before iter kt+1 restages it
    sb = (sb == 2 * BSZ) ? 0 : sb + BSZ;
    cb = (cb == 2 * BSZ) ? 0 : cb + BSZ;
  }
  // kt = 30: outstanding {t30,t31}=6 -> retire t30
  wait_vm<3>();
  BAR;
  COMPUTE(cb);  // cb = buf[30%3] = buf0
  // kt = 31: retire t31
  wait_vm<0>();
  BAR;
  COMPUTE(BSZ);  // buf[31%3] = buf1
#undef STG
#undef COMPUTE

  // C/D layout: col = r, row = q*4 + reg   [R8/R9-proven]
#pragma unroll
  for (int mi = 0; mi < 4; mi++) {
#pragma unroll
    for (int reg = 0; reg < 4; reg++) {
      int row = m0 + wm + mi * 16 + q * 4 + reg;
      float dv = EPI ? D[row] : 0.f;
#pragma unroll
      for (int ni = 0; ni < 4; ni++) {
        int col = n0 + wn + ni * 16 + r;
        size_t o = ((size_t)b * kM + row) * (size_t)kN + col;
        float v = acc[mi][ni][reg];
        if (EPI) {
          float y = v + dv * u[o];
          v = 0.5f * y * (1.f + erff(y * 0.70710678118654752f));
        }
        out[o] = v;
      }
    }
  }
}

// ---------------------------------------------------------------- scan (fp32 planar, in-place)
// [replay-proven]
__global__ __launch_bounds__(256) void k_scan(float* __restrict__ bu,
                                              const float2* __restrict__ lbar) {
  int p = blockIdx.x & (kP - 1);
  int b = blockIdx.x >> 9;
  int tid = threadIdx.x, lane = tid & 63, w = tid >> 6;
  float2 lam = lbar[p];
  float* sre = bu + ((size_t)b * kM + p) * (size_t)kN;
  float* sim = sre + (size_t)kP * kN;

  float vr[16], vi[16];
  {
    const float4* pr = (const float4*)(sre + tid * 16);
    const float4* pi = (const float4*)(sim + tid * 16);
#pragma unroll
    for (int i = 0; i < 4; i++) {
      float4 a = pr[i], c = pi[i];
      vr[4 * i] = a.x; vr[4 * i + 1] = a.y; vr[4 * i + 2] = a.z; vr[4 * i + 3] = a.w;
      vi[4 * i] = c.x; vi[4 * i + 1] = c.y; vi[4 * i + 2] = c.z; vi[4 * i + 3] = c.w;
    }
  }

  float xr = 0.f, xi = 0.f;
#pragma unroll
  for (int i = 0; i < 16; i++) {
    float nr2 = fmaf(lam.x, xr, fmaf(-lam.y, xi, vr[i]));
    float ni2 = fmaf(lam.x, xi, fmaf(lam.y, xr, vi[i]));
    xr = nr2; xi = ni2;
  }

  float Ar = lam.x, Ai = lam.y;
#pragma unroll
  for (int s = 0; s < 4; s++) {
    float tr = Ar * Ar - Ai * Ai, ti = 2.f * Ar * Ai;
    Ar = tr; Ai = ti;
  }
  float br = xr, bi = xi;

  for (int off = 1; off < 64; off <<= 1) {
    float pAr = __shfl_up(Ar, off), pAi = __shfl_up(Ai, off);
    float pbr = __shfl_up(br, off), pbi = __shfl_up(bi, off);
    if (lane >= off) {
      float nAr = Ar * pAr - Ai * pAi;
      float nAi = Ar * pAi + Ai * pAr;
      float nbr = Ar * pbr - Ai * pbi + br;
      float nbi = Ar * pbi + Ai * pbr + bi;
      Ar = nAr; Ai = nAi; br = nbr; bi = nbi;
    }
  }

  __shared__ float4 wtot[4];
  if (lane == 63) wtot[w] = make_float4(Ar, Ai, br, bi);
  __syncthreads();

  float eAr = __shfl_up(Ar, 1), eAi = __shfl_up(Ai, 1);
  float ebr = __shfl_up(br, 1), ebi = __shfl_up(bi, 1);
  if (lane == 0) { eAr = 1.f; eAi = 0.f; ebr = 0.f; ebi = 0.f; }

  float pAr = 1.f, pAi = 0.f, pbr = 0.f, pbi = 0.f;
  for (int j = 0; j < w; j++) {
    float4 t = wtot[j];
    float nAr = t.x * pAr - t.y * pAi;
    float nAi = t.x * pAi + t.y * pAr;
    float nbr = t.x * pbr - t.y * pbi + t.z;
    float nbi = t.x * pbi + t.y * pbr + t.w;
    pAr = nAr; pAi = nAi; pbr = nbr; pbi = nbi;
  }

  float initr = eAr * pbr - eAi * pbi + ebr;
  float initi = eAr * pbi + eAi * pbr + ebi;

  xr = initr; xi = initi;
  float4* qr = (float4*)(sre + tid * 16);
  float4* qi = (float4*)(sim + tid * 16);
#pragma unroll
  for (int i = 0; i < 4; i++) {
    float rr[4], ii[4];
#pragma unroll
    for (int j = 0; j < 4; j++) {
      float nr2 = fmaf(lam.x, xr, fmaf(-lam.y, xi, vr[4 * i + j]));
      float ni2 = fmaf(lam.x, xi, fmaf(lam.y, xr, vi[4 * i + j]));
      xr = nr2; xi = ni2; rr[j] = nr2; ii[j] = ni2;
    }
    qr[i] = make_float4(rr[0], rr[1], rr[2], rr[3]);
    qi[i] = make_float4(ii[0], ii[1], ii[2], ii[3]);
  }
}

// ================================================================ fp32 fallback
constexpr size_t OBBAR = 0;
constexpr size_t OLBAR = (size_t)kP * kH;
constexpr size_t OBU = OLBAR + 1024;

__global__ __launch_bounds__(256) void k_precomputeF(
    const float* __restrict__ Lre, const float* __restrict__ Lim,
    const float* __restrict__ B, const float* __restrict__ log_step,
    float2* __restrict__ ws) {
  int p = blockIdx.x;
  float lr = Lre[p], li = Lim[p];
  float step = expf(log_step[p]);
  float er = expf(lr * step);
  float sb, cb;
  sincosf(li * step, &sb, &cb);
  float lbr = er * cb, lbi = er * sb;
  float nr = lbr - 1.0f, ni = lbi;
  float inv = 1.0f / (lr * lr + li * li);
  float sr = (nr * lr + ni * li) * inv;
  float si = (ni * lr - nr * li) * inv;
  if (threadIdx.x == 0) ws[OLBAR + p] = make_float2(lbr, lbi);
  float2* Bbar = ws + OBBAR;
  const float* Brow = B + (size_t)p * kH * 2;
  for (int h = threadIdx.x; h < kH; h += 256) {
    float br = Brow[2 * h], bi = Brow[2 * h + 1];
    Bbar[(size_t)p * kH + h] = make_float2(sr * br - si * bi, sr * bi + si * br);
  }
}

__global__ __launch_bounds__(256) void k_gemm1F(
    const float2* __restrict__ ws_bbar, const float* __restrict__ u,
    float2* __restrict__ Bu) {
  __shared__ float2 As[16][64];
  __shared__ float Bs[16][64];
  int b = blockIdx.z, m0 = blockIdx.y * 64, n0 = blockIdx.x * 64;
  int tid = threadIdx.x, tn = tid & 15, tm = tid >> 4;
  const float* uB = u + (size_t)b * kH * kL;
  float2 acc[4][4];
#pragma unroll
  for (int i = 0; i < 4; i++)
#pragma unroll
    for (int j = 0; j < 4; j++) acc[i][j] = make_float2(0.f, 0.f);
  int ar = tid >> 2, ac = (tid & 3) * 4, bk = tid >> 4, bc = (tid & 15) * 4;
  for (int k0 = 0; k0 < kH; k0 += 16) {
    const float4* src = (const float4*)(ws_bbar + (size_t)(m0 + ar) * kH + k0 + ac);
    float4 v01 = src[0], v23 = src[1];
    As[ac + 0][ar] = make_float2(v01.x, v01.y);
    As[ac + 1][ar] = make_float2(v01.z, v01.w);
    As[ac + 2][ar] = make_float2(v23.x, v23.y);
    As[ac + 3][ar] = make_float2(v23.z, v23.w);
    float4 v = *(const float4*)(uB + (size_t)(k0 + bk) * kL + n0 + bc);
    *(float4*)&Bs[bk][bc] = v;
    __syncthreads();
#pragma unroll
    for (int kk = 0; kk < 16; ++kk) {
      const float4* arow = (const float4*)&As[kk][0];
      float4 a01 = arow[tm * 2 + 0], a23 = arow[tm * 2 + 1];
      float2 a[4] = {make_float2(a01.x, a01.y), make_float2(a01.z, a01.w),
                     make_float2(a23.x, a23.y), make_float2(a23.z, a23.w)};
      float4 bv = ((const float4*)&Bs[kk][0])[tn];
      float bbv[4] = {bv.x, bv.y, bv.z, bv.w};
#pragma unroll
      for (int mi = 0; mi < 4; mi++)
#pragma unroll
        for (int ni = 0; ni < 4; ni++) {
          acc[mi][ni].x = fmaf(a[mi].x, bbv[ni], acc[mi][ni].x);
          acc[mi][ni].y = fmaf(a[mi].y, bbv[ni], acc[mi][ni].y);
        }
    }
    __syncthreads();
  }
  float2* BuB = Bu + (size_t)b * kP * kL;
#pragma unroll
  for (int mi = 0; mi < 4; mi++) {
    int row = m0 + tm * 4 + mi;
    float2* dst = BuB + (size_t)row * kL + n0 + tn * 4;
    ((float4*)dst)[0] = make_float4(acc[mi][0].x, acc[mi][0].y, acc[mi][1].x, acc[mi][1].y);
    ((float4*)dst)[1] = make_float4(acc[mi][2].x, acc[mi][2].y, acc[mi][3].x, acc[mi][3].y);
  }
}

__global__ __launch_bounds__(256) void k_scanF(float2* __restrict__ Bu,
                                               const float2* __restrict__ Lbar) {
  int p = blockIdx.x & (kP - 1);
  int b = blockIdx.x >> 9;
  int tid = threadIdx.x, lane = tid & 63, w = tid >> 6;
  float2 lam = Lbar[p];
  float2* seq = Bu + ((size_t)b * kP + p) * kL;
  float2 v[16];
  const float4* src = (const float4*)(seq + tid * 16);
#pragma unroll
  for (int i = 0; i < 8; i++) {
    float4 t = src[i];
    v[2 * i] = make_float2(t.x, t.y);
    v[2 * i + 1] = make_float2(t.z, t.w);
  }
  float xr = 0.f, xi = 0.f;
#pragma unroll
  for (int i = 0; i < 16; i++) {
    float nr2 = fmaf(lam.x, xr, fmaf(-lam.y, xi, v[i].x));
    float ni2 = fmaf(lam.x, xi, fmaf(lam.y, xr, v[i].y));
    xr = nr2; xi = ni2;
  }
  float Ar = lam.x, Ai = lam.y;
#pragma unroll
  for (int s = 0; s < 4; s++) {
    float tr = Ar * Ar - Ai * Ai, ti = 2.f * Ar * Ai;
    Ar = tr; Ai = ti;
  }
  float br = xr, bi = xi;
  for (int off = 1; off < 64; off <<= 1) {
    float pAr = __shfl_up(Ar, off), pAi = __shfl_up(Ai, off);
    float pbr = __shfl_up(br, off), pbi = __shfl_up(bi, off);
    if (lane >= off) {
      float nAr = Ar * pAr - Ai * pAi, nAi = Ar * pAi + Ai * pAr;
      float nbr = Ar * pbr - Ai * pbi + br, nbi = Ar * pbi + Ai * pbr + bi;
      Ar = nAr; Ai = nAi; br = nbr; bi = nbi;
    }
  }
  __shared__ float4 wtot[4];
  if (lane == 63) wtot[w] = make_float4(Ar, Ai, br, bi);
  __syncthreads();
  float eAr = __shfl_up(Ar, 1), eAi = __shfl_up(Ai, 1);
  float ebr = __shfl_up(br, 1), ebi = __shfl_up(bi, 1);
  if (lane == 0) { eAr = 1.f; eAi = 0.f; ebr = 0.f; ebi = 0.f; }
  float pAr = 1.f, pAi = 0.f, pbr = 0.f, pbi = 0.f;
  for (int j = 0; j < w; j++) {
    float4 t = wtot[j];
    float nAr = t.x * pAr - t.y * pAi, nAi = t.x * pAi + t.y * pAr;
    float nbr = t.x * pbr - t.y * pbi + t.z, nbi = t.x * pbi + t.y * pbr + t.w;
    pAr = nAr; pAi = nAi; pbr = nbr; pbi = nbi;
  }
  float initr = eAr * pbr - eAi * pbi + ebr;
  float initi = eAr * pbi + eAi * pbr + ebi;
  xr = initr; xi = initi;
  float4* dst = (float4*)(seq + tid * 16);
#pragma unroll
  for (int i = 0; i < 8; i++) {
    float nr0 = fmaf(lam.x, xr, fmaf(-lam.y, xi, v[2 * i].x));
    float ni0 = fmaf(lam.x, xi, fmaf(lam.y, xr, v[2 * i].y));
    float nr1 = fmaf(lam.x, nr0, fmaf(-lam.y, ni0, v[2 * i + 1].x));
    float ni1 = fmaf(lam.x, ni0, fmaf(lam.y, nr0, v[2 * i + 1].y));
    dst[i] = make_float4(nr0, ni0, nr1, ni1);
    xr = nr1; xi = ni1;
  }
}

__global__ __launch_bounds__(256) void k_gemm2F(
    const float2* __restrict__ C, const float2* __restrict__ X,
    const float* __restrict__ u, const float* __restrict__ D,
    float* __restrict__ out) {
  __shared__ float2 As[16][64];
  __shared__ float2 Bs[16][64];
  int b = blockIdx.z, m0 = blockIdx.y * 64, n0 = blockIdx.x * 64;
  int tid = threadIdx.x, tn = tid & 15, tm = tid >> 4;
  const float2* Xb = X + (size_t)b * kP * kL;
  float acc[4][4];
#pragma unroll
  for (int i = 0; i < 4; i++)
#pragma unroll
    for (int j = 0; j < 4; j++) acc[i][j] = 0.f;
  int ar = tid >> 2, ac = (tid & 3) * 4, bk = tid >> 4, bc = (tid & 15) * 4;
  for (int k0 = 0; k0 < kP; k0 += 16) {
    const float4* src = (const float4*)(C + (size_t)(m0 + ar) * kP + k0 + ac);
    float4 v01 = src[0], v23 = src[1];
    As[ac + 0][ar] = make_float2(v01.x, v01.y);
    As[ac + 1][ar] = make_float2(v01.z, v01.w);
    As[ac + 2][ar] = make_float2(v23.x, v23.y);
    As[ac + 3][ar] = make_float2(v23.z, v23.w);
    const float4* srcb = (const float4*)(Xb + (size_t)(k0 + bk) * kL + n0 + bc);
    ((float4*)&Bs[bk][bc])[0] = srcb[0];
    ((float4*)&Bs[bk][bc])[1] = srcb[1];
    __syncthreads();
#pragma unroll
    for (int kk = 0; kk < 16; ++kk) {
      const float4* arow = (const float4*)&As[kk][0];
      float4 a01 = arow[tm * 2 + 0], a23 = arow[tm * 2 + 1];
      float2 a[4] = {make_float2(a01.x, a01.y), make_float2(a01.z, a01.w),
                     make_float2(a23.x, a23.y), make_float2(a23.z, a23.w)};
      const float4* brow = (const float4*)&Bs[kk][0];
      float4 b01 = brow[tn * 2 + 0], b23 = brow[tn * 2 + 1];
      float2 bbv[4] = {make_float2(b01.x, b01.y), make_float2(b01.z, b01.w),
                       make_float2(b23.x, b23.y), make_float2(b23.z, b23.w)};
#pragma unroll
      for (int mi = 0; mi < 4; mi++)
#pragma unroll
        for (int ni = 0; ni < 4; ni++) {
          acc[mi][ni] = fmaf(a[mi].x, bbv[ni].x, acc[mi][ni]);
          acc[mi][ni] = fmaf(-a[mi].y, bbv[ni].y, acc[mi][ni]);
        }
    }
    __syncthreads();
  }
#pragma unroll
  for (int mi = 0; mi < 4; mi++) {
    int h = m0 + tm * 4 + mi;
    float d = D[h];
    const float* urow = u + ((size_t)b * kH + h) * kL + n0 + tn * 4;
    float4 uv = *(const float4*)urow;
    float uu[4] = {uv.x, uv.y, uv.z, uv.w};
    float res[4];
#pragma unroll
    for (int ni = 0; ni < 4; ni++) {
      float y = 2.f * acc[mi][ni] + d * uu[ni];
      res[ni] = 0.5f * y * (1.f + erff(y * 0.70710678118654752f));
    }
    float* orow = out + ((size_t)b * kH + h) * kL + n0 + tn * 4;
    *(float4*)orow = make_float4(res[0], res[1], res[2], res[3]);
  }
}

// ---------------------------------------------------------------- launch
extern "C" void kernel_launch(void* const* d_in, const int* in_sizes, int n_in,
                              void* d_out, int out_size, void* d_ws, size_t ws_size,
                              hipStream_t stream) {
  const float* input_sequence = (const float*)d_in[0];
  const float* Lambda_re = (const float*)d_in[2];
  const float* Lambda_im = (const float*)d_in[3];
  const float* B = (const float*)d_in[4];
  const float* C = (const float*)d_in[5];
  const float* D = (const float*)d_in[6];
  const float* log_step = (const float*)d_in[7];
  float* out = (float*)d_out;

  if (ws_size >= MID_BYTES) {
    unsigned char* ws = (unsigned char*)d_ws;
    unsigned short* a1h = (unsigned short*)(ws + A1H_OFF);
    unsigned short* a2h = (unsigned short*)(ws + A2H_OFF);
    float2* lbar = (float2*)(ws + LBAR_B);
    float* bu = (float*)(ws + BU_B);
    unsigned short* th = (unsigned short*)(ws + TH_B);

    k_prep12<<<dim3(kP + kH), 256, 0, stream>>>(Lambda_re, Lambda_im, B,
                                                log_step, C, ws);

    dim3 tgrid(kL / 64, 1024 / 64, kB);
    dim3 ggrid(kN / 256, kM / 128, kB);  // 16 x 8 x 4 = 512 blocks

    k_transpose<<<tgrid, 256, 0, stream>>>(input_sequence, th);
    k_gemm3b<false><<<ggrid, 512, 0, stream>>>(a1h, th, bu, nullptr, nullptr);
    k_scan<<<dim3(kB * kP), 256, 0, stream>>>(bu, lbar);
    k_transpose<<<tgrid, 256, 0, stream>>>(bu, th);
    k_gemm3b<true><<<ggrid, 512, 0, stream>>>(a2h, th, out, input_sequence, D);
  } else {
    // fp32 fallback (round-1 path)
    float2* ws = (float2*)d_ws;
    float2* Bbar = ws + OBBAR;
    float2* Lbar = ws + OLBAR;
    float2* Bu = ws + OBU;
    k_precomputeF<<<dim3(kP), 256, 0, stream>>>(Lambda_re, Lambda_im, B, log_step, ws);
    k_gemm1F<<<dim3(kL / 64, kP / 64, kB), 256, 0, stream>>>(Bbar, input_sequence, Bu);
    k_scanF<<<dim3(kB * kP), 256, 0, stream>>>(Bu, Lbar);
    k_gemm2F<<<dim3(kL / 64, kH / 64, kB), 256, 0, stream>>>(
        (const float2*)C, (const float2*)Bu, input_sequence, D, out);
  }
}

// Round 8
// 272.657 us; speedup vs baseline: 1.1646x; 1.0472x over previous
//
#include <hip/hip_runtime.h>
#include <math.h>

// S5 SSM forward — R12: R9 GEMM (best measured, 65.0us) + trimmed mid-pipeline.
// R11 post-mortem: 3-buffer counted-vmcnt ring was FLAT-to-worse (68.3 vs 65.0)
// -> per pre-registered falsification, the vmcnt drain was not binding; the
// 128x256/BK32 GEMM is at its structural floor (~65us). GEMM experiments
// stopped; revert to R9's k_gemm2p verbatim.
// New this round (non-GEMM traffic cuts, all deterministic):
//  - k_scan writes bf16 planar xs directly (f2bf = same rounding transpose2
//    applied) and drops the fp32 writeback: 128 -> 96 MB.
//  - transpose2 becomes bf16->bf16 (k_transpose_h): 96 -> 64 MB.
//  - buffer reuse: scan -> th region; transpose_h -> bu region; gemm2 reads it.
// BSZ=4, L=4096, H=1024, P=512.

constexpr int kB = 4, kL = 4096, kH = 1024, kP = 512;
constexpr int kM = 1024, kK = 1024, kN = 4096;

typedef short bf16x8 __attribute__((ext_vector_type(8)));
typedef float f32x4 __attribute__((ext_vector_type(4)));

// ---- ws layout (bytes), MFMA path
constexpr size_t A1H_OFF = 0;                                    // 2 MiB
constexpr size_t A2H_OFF = A1H_OFF + (size_t)kM * kK * 2;        // 2 MiB
constexpr size_t LBAR_B  = A2H_OFF + (size_t)kM * kK * 2;        // 4 KiB
constexpr size_t BU_B    = (LBAR_B + 4096 + 255) & ~(size_t)255; // 64 MiB fp32
constexpr size_t TH_B    = BU_B + (size_t)kB * kM * kN * 4;      // 32 MiB bf16
constexpr size_t MID_BYTES = TH_B + (size_t)kB * kN * kK * 2;    // ~100 MiB

// ---- bf16 helpers
__device__ __forceinline__ unsigned short f2bf(float x) {
  unsigned int u = __float_as_uint(x);
  u += 0x7fffu + ((u >> 16) & 1u);
  return (unsigned short)(u >> 16);
}
__device__ __forceinline__ float bf2f(unsigned short h) {
  return __uint_as_float(((unsigned int)h) << 16);
}

__device__ __forceinline__ void gl2lds16(const void* g, void* l) {
  __builtin_amdgcn_global_load_lds(
      (const __attribute__((address_space(1))) void*)g,
      (__attribute__((address_space(3))) void*)l, 16, 0, 0);
}

// s_waitcnt with vmcnt=N, lgkmcnt/expcnt = don't-care
template <int N>
__device__ __forceinline__ void wait_vm() {
  __builtin_amdgcn_s_waitcnt((N & 15) | ((N >> 4) << 14) | (15 << 8) | (7 << 4));
}

// ---------------------------------------------------------------- prep (merged)
// blocks 0..511: prep1 (p = bid); blocks 512..1535: prep2 (h = bid-512)
__global__ __launch_bounds__(256) void k_prep12(
    const float* __restrict__ Lre, const float* __restrict__ Lim,
    const float* __restrict__ B, const float* __restrict__ log_step,
    const float* __restrict__ C, unsigned char* __restrict__ ws) {
  int bid = blockIdx.x;
  if (bid < kP) {
    int p = bid;
    float lr = Lre[p], li = Lim[p];
    float step = expf(log_step[p]);
    float er = expf(lr * step);
    float sb, cb;
    sincosf(li * step, &sb, &cb);
    float lbr = er * cb, lbi = er * sb;
    float nr = lbr - 1.0f, ni = lbi;
    float inv = 1.0f / (lr * lr + li * li);
    float sr = (nr * lr + ni * li) * inv;
    float si = (ni * lr - nr * li) * inv;

    if (threadIdx.x == 0) ((float2*)(ws + LBAR_B))[p] = make_float2(lbr, lbi);

    unsigned short* a1h = (unsigned short*)(ws + A1H_OFF);
    const float* Brow = B + (size_t)p * kH * 2;
    for (int h = threadIdx.x; h < kH; h += 256) {
      float br = Brow[2 * h], bi = Brow[2 * h + 1];
      a1h[(size_t)p * kK + h] = f2bf(sr * br - si * bi);
      a1h[(size_t)(kP + p) * kK + h] = f2bf(sr * bi + si * br);
    }
  } else {
    int h = bid - kP;
    unsigned short* a2h = (unsigned short*)(ws + A2H_OFF);
    for (int k = threadIdx.x; k < kK; k += 256) {
      float v = (k < kP) ? 2.f * C[((size_t)h * kP + k) * 2]
                         : -2.f * C[((size_t)h * kP + (k - kP)) * 2 + 1];
      a2h[(size_t)h * kK + k] = f2bf(v);
    }
  }
}

// ---------------------------------------------------------------- transpose (fp32 -> bf16T)
// in: fp32 [b][1024][4096] -> out: bf16 [b][4096][1024]   [replay-proven]
__global__ __launch_bounds__(256) void k_transpose(
    const float* __restrict__ in, unsigned short* __restrict__ oh) {
  __shared__ float t[64][65];
  int b = blockIdx.z;
  int r0 = blockIdx.y * 64;
  int c0 = blockIdx.x * 64;
  int tid = threadIdx.x;
  const float* src = in + ((size_t)b * 1024 + r0) * 4096 + c0;
  int cc = (tid & 15) * 4, rr = tid >> 4;
#pragma unroll
  for (int i = 0; i < 4; i++) {
    float4 v = *(const float4*)(src + (size_t)(rr + i * 16) * 4096 + cc);
    t[rr + i * 16][cc + 0] = v.x;
    t[rr + i * 16][cc + 1] = v.y;
    t[rr + i * 16][cc + 2] = v.z;
    t[rr + i * 16][cc + 3] = v.w;
  }
  __syncthreads();
  int oc = tid >> 2;
  int og = (tid & 3) * 2;
#pragma unroll
  for (int i = 0; i < 2; i++) {
    int g = og + i;
    unsigned short hv[8];
#pragma unroll
    for (int j = 0; j < 8; j++) hv[j] = f2bf(t[g * 8 + j][oc]);
    size_t ob = ((size_t)b * 4096 + c0 + oc) * 1024 + r0 + g * 8;
    *(uint4*)(oh + ob) = *(uint4*)hv;
  }
}

// ---------------------------------------------------------------- transpose (bf16 -> bf16T)
// in: bf16 [b][1024][4096] -> out: bf16 [b][4096][1024]
// Same LDS/store structure as k_transpose (replay-proven write side);
// load side reads bf16x8 and widens. f2bf(bf2f(x)) == x exactly.
__global__ __launch_bounds__(256) void k_transpose_h(
    const unsigned short* __restrict__ in, unsigned short* __restrict__ oh) {
  __shared__ float t[64][65];
  int b = blockIdx.z;
  int r0 = blockIdx.y * 64;
  int c0 = blockIdx.x * 64;
  int tid = threadIdx.x;
  const unsigned short* src = in + ((size_t)b * 1024 + r0) * 4096 + c0;
  int cc = (tid & 7) * 8, rr = tid >> 3;  // rr 0..31
#pragma unroll
  for (int i = 0; i < 2; i++) {
    bf16x8 v = *(const bf16x8*)(src + (size_t)(rr + i * 32) * 4096 + cc);
#pragma unroll
    for (int j = 0; j < 8; j++)
      t[rr + i * 32][cc + j] = bf2f((unsigned short)v[j]);
  }
  __syncthreads();
  int oc = tid >> 2;
  int og = (tid & 3) * 2;
#pragma unroll
  for (int i = 0; i < 2; i++) {
    int g = og + i;
    unsigned short hv[8];
#pragma unroll
    for (int j = 0; j < 8; j++) hv[j] = f2bf(t[g * 8 + j][oc]);
    size_t ob = ((size_t)b * 4096 + c0 + oc) * 1024 + r0 + g * 8;
    *(uint4*)(oh + ob) = *(uint4*)hv;
  }
}

// ================================================================ 2-phase GEMM
// R9 verbatim (best measured 65.0us): 128x256 tile, BK=32, 8 waves of 64x64,
// 48 KiB LDS (2 bufs), st_16x32 swizzle, gl_lds linear-dest + inv-swz source,
// 1 barrier + 1 vmcnt(0) per K-tile.

__device__ __forceinline__ int stage_src_off32(int Dp) {
  int Ds = Dp ^ (((Dp >> 9) & 1) << 5);  // involution
  int s = Ds >> 10, d = Ds & 1023;       // subtile (row-block), within-subtile
  int row = (s << 4) + (d >> 6);         // 0..127
  int kk = (d & 63) >> 1;                // 0..31 (multiple of 8)
  return row * kK + kk;
}

#define BAR __builtin_amdgcn_s_barrier()
#define LGKM0                                           \
  do {                                                  \
    asm volatile("s_waitcnt lgkmcnt(0)" ::: "memory");  \
    __builtin_amdgcn_sched_barrier(0);                  \
  } while (0)

template <bool EPI>
__global__ __launch_bounds__(512, 4) void k_gemm2p(
    const unsigned short* __restrict__ Ah, const unsigned short* __restrict__ Bh,
    float* __restrict__ out, const float* __restrict__ u,
    const float* __restrict__ D) {
  __shared__ __align__(16) unsigned char lds[49152];
  constexpr int BUF = 24576;
  constexpr int NKT = kK / 32;  // 32 K-tiles

  int b = blockIdx.z;
  int m0 = blockIdx.y * 128, n0 = blockIdx.x * 256;
  int tid = threadIdx.x, w = tid >> 6;
  int q = (tid >> 4) & 3, r = tid & 15;
  int wm = (w >> 2) * 64, wn = (w & 3) * 64;
  int wmrb = (w >> 2) * 4, wnrb = (w & 3) * 4;
  int lane_off = (r * 64 + q * 16) ^ ((r & 8) << 2);  // st_16x32 read swizzle

  int d0 = tid << 4;
  int rowk = stage_src_off32(d0);  // same decode for A piece and each B half

  const unsigned short* pA = Ah + (size_t)m0 * kK;
  const unsigned short* pB = Bh + (size_t)b * kN * kK + (size_t)n0 * kK;

  f32x4 acc[4][4] = {};

  // one K-tile stage: A 8KB (rows 0-127) + B 16KB (two 8KB halves)
#define STG(KT, LB)                                                       \
  do {                                                                    \
    gl2lds16(pA + (KT) * 32 + rowk, lds + (LB) + d0);                     \
    gl2lds16(pB + (KT) * 32 + rowk, lds + (LB) + 8192 + d0);              \
    gl2lds16(pB + (size_t)128 * kK + (KT) * 32 + rowk,                    \
             lds + (LB) + 16384 + d0);                                    \
  } while (0)

  // one K-tile compute: 4 A-frags + 4 B-frags -> 16 MFMA into acc
#define COMPUTE(LB)                                                       \
  do {                                                                    \
    bf16x8 a[4], bb[4];                                                   \
    _Pragma("unroll")                                                     \
    for (int mi = 0; mi < 4; mi++)                                        \
      a[mi] = *(const bf16x8*)(lds + (LB) + ((wmrb + mi) << 10) + lane_off); \
    _Pragma("unroll")                                                     \
    for (int nj = 0; nj < 4; nj++)                                        \
      bb[nj] = *(const bf16x8*)(lds + (LB) + 8192 +                       \
                                ((wnrb + nj) << 10) + lane_off);          \
    LGKM0;                                                                \
    __builtin_amdgcn_s_setprio(1);                                        \
    _Pragma("unroll")                                                     \
    for (int mi = 0; mi < 4; mi++)                                        \
      _Pragma("unroll")                                                   \
      for (int nj = 0; nj < 4; nj++)                                      \
        acc[mi][nj] = __builtin_amdgcn_mfma_f32_16x16x32_bf16(            \
            a[mi], bb[nj], acc[mi][nj], 0, 0, 0);                         \
    __builtin_amdgcn_s_setprio(0);                                        \
  } while (0)

  // prologue: buf0 <- kt0
  STG(0, 0);
  wait_vm<0>();
  BAR;

  for (int it = 0; it < NKT / 2; ++it) {
    int kt = it * 2;
    // phase A: stage buf1 <- kt+1; compute buf0 (kt)
    if (kt + 1 < NKT) STG(kt + 1, BUF);
    COMPUTE(0);
    wait_vm<0>();  // kt+1 loads landed (had full MFMA phase to fly)
    BAR;           // also fences: all reads of buf0 done -> safe to restage
    // phase B: stage buf0 <- kt+2; compute buf1 (kt+1)
    if (kt + 2 < NKT) STG(kt + 2, 0);
    COMPUTE(BUF);
    wait_vm<0>();
    BAR;
  }
#undef STG
#undef COMPUTE

  // C/D layout: col = r, row = q*4 + reg   [R8/R9-proven]
#pragma unroll
  for (int mi = 0; mi < 4; mi++) {
#pragma unroll
    for (int reg = 0; reg < 4; reg++) {
      int row = m0 + wm + mi * 16 + q * 4 + reg;
      float dv = EPI ? D[row] : 0.f;
#pragma unroll
      for (int ni = 0; ni < 4; ni++) {
        int col = n0 + wn + ni * 16 + r;
        size_t o = ((size_t)b * kM + row) * (size_t)kN + col;
        float v = acc[mi][ni][reg];
        if (EPI) {
          float y = v + dv * u[o];
          v = 0.5f * y * (1.f + erff(y * 0.70710678118654752f));
        }
        out[o] = v;
      }
    }
  }
}

// ---------------------------------------------------------------- scan
// fp32 planar in (bu, read-only), bf16 planar out (xsh) — the f2bf rounding
// is identical to what the old transpose2 applied, so final numerics match.
__global__ __launch_bounds__(256) void k_scan(const float* __restrict__ bu,
                                              const float2* __restrict__ lbar,
                                              unsigned short* __restrict__ xsh) {
  int p = blockIdx.x & (kP - 1);
  int b = blockIdx.x >> 9;
  int tid = threadIdx.x, lane = tid & 63, w = tid >> 6;
  float2 lam = lbar[p];
  const float* sre = bu + ((size_t)b * kM + p) * (size_t)kN;
  const float* sim = sre + (size_t)kP * kN;

  float vr[16], vi[16];
  {
    const float4* pr = (const float4*)(sre + tid * 16);
    const float4* pi = (const float4*)(sim + tid * 16);
#pragma unroll
    for (int i = 0; i < 4; i++) {
      float4 a = pr[i], c = pi[i];
      vr[4 * i] = a.x; vr[4 * i + 1] = a.y; vr[4 * i + 2] = a.z; vr[4 * i + 3] = a.w;
      vi[4 * i] = c.x; vi[4 * i + 1] = c.y; vi[4 * i + 2] = c.z; vi[4 * i + 3] = c.w;
    }
  }

  float xr = 0.f, xi = 0.f;
#pragma unroll
  for (int i = 0; i < 16; i++) {
    float nr2 = fmaf(lam.x, xr, fmaf(-lam.y, xi, vr[i]));
    float ni2 = fmaf(lam.x, xi, fmaf(lam.y, xr, vi[i]));
    xr = nr2; xi = ni2;
  }

  float Ar = lam.x, Ai = lam.y;
#pragma unroll
  for (int s = 0; s < 4; s++) {
    float tr = Ar * Ar - Ai * Ai, ti = 2.f * Ar * Ai;
    Ar = tr; Ai = ti;
  }
  float br = xr, bi = xi;

  for (int off = 1; off < 64; off <<= 1) {
    float pAr = __shfl_up(Ar, off), pAi = __shfl_up(Ai, off);
    float pbr = __shfl_up(br, off), pbi = __shfl_up(bi, off);
    if (lane >= off) {
      float nAr = Ar * pAr - Ai * pAi;
      float nAi = Ar * pAi + Ai * pAr;
      float nbr = Ar * pbr - Ai * pbi + br;
      float nbi = Ar * pbi + Ai * pbr + bi;
      Ar = nAr; Ai = nAi; br = nbr; bi = nbi;
    }
  }

  __shared__ float4 wtot[4];
  if (lane == 63) wtot[w] = make_float4(Ar, Ai, br, bi);
  __syncthreads();

  float eAr = __shfl_up(Ar, 1), eAi = __shfl_up(Ai, 1);
  float ebr = __shfl_up(br, 1), ebi = __shfl_up(bi, 1);
  if (lane == 0) { eAr = 1.f; eAi = 0.f; ebr = 0.f; ebi = 0.f; }

  float pAr = 1.f, pAi = 0.f, pbr = 0.f, pbi = 0.f;
  for (int j = 0; j < w; j++) {
    float4 t = wtot[j];
    float nAr = t.x * pAr - t.y * pAi;
    float nAi = t.x * pAi + t.y * pAr;
    float nbr = t.x * pbr - t.y * pbi + t.z;
    float nbi = t.x * pbi + t.y * pbr + t.w;
    pAr = nAr; pAi = nAi; pbr = nbr; pbi = nbi;
  }

  float initr = eAr * pbr - eAi * pbi + ebr;
  float initi = eAr * pbi + eAi * pbr + ebi;

  xr = initr; xi = initi;
  __align__(16) unsigned short hr[16], him[16];
#pragma unroll
  for (int i = 0; i < 16; i++) {
    float nr2 = fmaf(lam.x, xr, fmaf(-lam.y, xi, vr[i]));
    float ni2 = fmaf(lam.x, xi, fmaf(lam.y, xr, vi[i]));
    xr = nr2; xi = ni2;
    hr[i] = f2bf(nr2); him[i] = f2bf(ni2);
  }
  unsigned short* drh = xsh + ((size_t)b * kM + p) * (size_t)kN + tid * 16;
  unsigned short* dih = drh + (size_t)kP * kN;
  ((uint4*)drh)[0] = *(uint4*)&hr[0];
  ((uint4*)drh)[1] = *(uint4*)&hr[8];
  ((uint4*)dih)[0] = *(uint4*)&him[0];
  ((uint4*)dih)[1] = *(uint4*)&him[8];
}

// ================================================================ fp32 fallback
constexpr size_t OBBAR = 0;
constexpr size_t OLBAR = (size_t)kP * kH;
constexpr size_t OBU = OLBAR + 1024;

__global__ __launch_bounds__(256) void k_precomputeF(
    const float* __restrict__ Lre, const float* __restrict__ Lim,
    const float* __restrict__ B, const float* __restrict__ log_step,
    float2* __restrict__ ws) {
  int p = blockIdx.x;
  float lr = Lre[p], li = Lim[p];
  float step = expf(log_step[p]);
  float er = expf(lr * step);
  float sb, cb;
  sincosf(li * step, &sb, &cb);
  float lbr = er * cb, lbi = er * sb;
  float nr = lbr - 1.0f, ni = lbi;
  float inv = 1.0f / (lr * lr + li * li);
  float sr = (nr * lr + ni * li) * inv;
  float si = (ni * lr - nr * li) * inv;
  if (threadIdx.x == 0) ws[OLBAR + p] = make_float2(lbr, lbi);
  float2* Bbar = ws + OBBAR;
  const float* Brow = B + (size_t)p * kH * 2;
  for (int h = threadIdx.x; h < kH; h += 256) {
    float br = Brow[2 * h], bi = Brow[2 * h + 1];
    Bbar[(size_t)p * kH + h] = make_float2(sr * br - si * bi, sr * bi + si * br);
  }
}

__global__ __launch_bounds__(256) void k_gemm1F(
    const float2* __restrict__ ws_bbar, const float* __restrict__ u,
    float2* __restrict__ Bu) {
  __shared__ float2 As[16][64];
  __shared__ float Bs[16][64];
  int b = blockIdx.z, m0 = blockIdx.y * 64, n0 = blockIdx.x * 64;
  int tid = threadIdx.x, tn = tid & 15, tm = tid >> 4;
  const float* uB = u + (size_t)b * kH * kL;
  float2 acc[4][4];
#pragma unroll
  for (int i = 0; i < 4; i++)
#pragma unroll
    for (int j = 0; j < 4; j++) acc[i][j] = make_float2(0.f, 0.f);
  int ar = tid >> 2, ac = (tid & 3) * 4, bk = tid >> 4, bc = (tid & 15) * 4;
  for (int k0 = 0; k0 < kH; k0 += 16) {
    const float4* src = (const float4*)(ws_bbar + (size_t)(m0 + ar) * kH + k0 + ac);
    float4 v01 = src[0], v23 = src[1];
    As[ac + 0][ar] = make_float2(v01.x, v01.y);
    As[ac + 1][ar] = make_float2(v01.z, v01.w);
    As[ac + 2][ar] = make_float2(v23.x, v23.y);
    As[ac + 3][ar] = make_float2(v23.z, v23.w);
    float4 v = *(const float4*)(uB + (size_t)(k0 + bk) * kL + n0 + bc);
    *(float4*)&Bs[bk][bc] = v;
    __syncthreads();
#pragma unroll
    for (int kk = 0; kk < 16; ++kk) {
      const float4* arow = (const float4*)&As[kk][0];
      float4 a01 = arow[tm * 2 + 0], a23 = arow[tm * 2 + 1];
      float2 a[4] = {make_float2(a01.x, a01.y), make_float2(a01.z, a01.w),
                     make_float2(a23.x, a23.y), make_float2(a23.z, a23.w)};
      float4 bv = ((const float4*)&Bs[kk][0])[tn];
      float bbv[4] = {bv.x, bv.y, bv.z, bv.w};
#pragma unroll
      for (int mi = 0; mi < 4; mi++)
#pragma unroll
        for (int ni = 0; ni < 4; ni++) {
          acc[mi][ni].x = fmaf(a[mi].x, bbv[ni], acc[mi][ni].x);
          acc[mi][ni].y = fmaf(a[mi].y, bbv[ni], acc[mi][ni].y);
        }
    }
    __syncthreads();
  }
  float2* BuB = Bu + (size_t)b * kP * kL;
#pragma unroll
  for (int mi = 0; mi < 4; mi++) {
    int row = m0 + tm * 4 + mi;
    float2* dst = BuB + (size_t)row * kL + n0 + tn * 4;
    ((float4*)dst)[0] = make_float4(acc[mi][0].x, acc[mi][0].y, acc[mi][1].x, acc[mi][1].y);
    ((float4*)dst)[1] = make_float4(acc[mi][2].x, acc[mi][2].y, acc[mi][3].x, acc[mi][3].y);
  }
}

__global__ __launch_bounds__(256) void k_scanF(float2* __restrict__ Bu,
                                               const float2* __restrict__ Lbar) {
  int p = blockIdx.x & (kP - 1);
  int b = blockIdx.x >> 9;
  int tid = threadIdx.x, lane = tid & 63, w = tid >> 6;
  float2 lam = Lbar[p];
  float2* seq = Bu + ((size_t)b * kP + p) * kL;
  float2 v[16];
  const float4* src = (const float4*)(seq + tid * 16);
#pragma unroll
  for (int i = 0; i < 8; i++) {
    float4 t = src[i];
    v[2 * i] = make_float2(t.x, t.y);
    v[2 * i + 1] = make_float2(t.z, t.w);
  }
  float xr = 0.f, xi = 0.f;
#pragma unroll
  for (int i = 0; i < 16; i++) {
    float nr2 = fmaf(lam.x, xr, fmaf(-lam.y, xi, v[i].x));
    float ni2 = fmaf(lam.x, xi, fmaf(lam.y, xr, v[i].y));
    xr = nr2; xi = ni2;
  }
  float Ar = lam.x, Ai = lam.y;
#pragma unroll
  for (int s = 0; s < 4; s++) {
    float tr = Ar * Ar - Ai * Ai, ti = 2.f * Ar * Ai;
    Ar = tr; Ai = ti;
  }
  float br = xr, bi = xi;
  for (int off = 1; off < 64; off <<= 1) {
    float pAr = __shfl_up(Ar, off), pAi = __shfl_up(Ai, off);
    float pbr = __shfl_up(br, off), pbi = __shfl_up(bi, off);
    if (lane >= off) {
      float nAr = Ar * pAr - Ai * pAi, nAi = Ar * pAi + Ai * pAr;
      float nbr = Ar * pbr - Ai * pbi + br, nbi = Ar * pbi + Ai * pbr + bi;
      Ar = nAr; Ai = nAi; br = nbr; bi = nbi;
    }
  }
  __shared__ float4 wtot[4];
  if (lane == 63) wtot[w] = make_float4(Ar, Ai, br, bi);
  __syncthreads();
  float eAr = __shfl_up(Ar, 1), eAi = __shfl_up(Ai, 1);
  float ebr = __shfl_up(br, 1), ebi = __shfl_up(bi, 1);
  if (lane == 0) { eAr = 1.f; eAi = 0.f; ebr = 0.f; ebi = 0.f; }
  float pAr = 1.f, pAi = 0.f, pbr = 0.f, pbi = 0.f;
  for (int j = 0; j < w; j++) {
    float4 t = wtot[j];
    float nAr = t.x * pAr - t.y * pAi, nAi = t.x * pAi + t.y * pAr;
    float nbr = t.x * pbr - t.y * pbi + t.z, nbi = t.x * pbi + t.y * pbr + t.w;
    pAr = nAr; pAi = nAi; pbr = nbr; pbi = nbi;
  }
  float initr = eAr * pbr - eAi * pbi + ebr;
  float initi = eAr * pbi + eAi * pbr + ebi;
  xr = initr; xi = initi;
  float4* dst = (float4*)(seq + tid * 16);
#pragma unroll
  for (int i = 0; i < 8; i++) {
    float nr0 = fmaf(lam.x, xr, fmaf(-lam.y, xi, v[2 * i].x));
    float ni0 = fmaf(lam.x, xi, fmaf(lam.y, xr, v[2 * i].y));
    float nr1 = fmaf(lam.x, nr0, fmaf(-lam.y, ni0, v[2 * i + 1].x));
    float ni1 = fmaf(lam.x, ni0, fmaf(lam.y, nr0, v[2 * i + 1].y));
    dst[i] = make_float4(nr0, ni0, nr1, ni1);
    xr = nr1; xi = ni1;
  }
}

__global__ __launch_bounds__(256) void k_gemm2F(
    const float2* __restrict__ C, const float2* __restrict__ X,
    const float* __restrict__ u, const float* __restrict__ D,
    float* __restrict__ out) {
  __shared__ float2 As[16][64];
  __shared__ float2 Bs[16][64];
  int b = blockIdx.z, m0 = blockIdx.y * 64, n0 = blockIdx.x * 64;
  int tid = threadIdx.x, tn = tid & 15, tm = tid >> 4;
  const float2* Xb = X + (size_t)b * kP * kL;
  float acc[4][4];
#pragma unroll
  for (int i = 0; i < 4; i++)
#pragma unroll
    for (int j = 0; j < 4; j++) acc[i][j] = 0.f;
  int ar = tid >> 2, ac = (tid & 3) * 4, bk = tid >> 4, bc = (tid & 15) * 4;
  for (int k0 = 0; k0 < kP; k0 += 16) {
    const float4* src = (const float4*)(C + (size_t)(m0 + ar) * kP + k0 + ac);
    float4 v01 = src[0], v23 = src[1];
    As[ac + 0][ar] = make_float2(v01.x, v01.y);
    As[ac + 1][ar] = make_float2(v01.z, v01.w);
    As[ac + 2][ar] = make_float2(v23.x, v23.y);
    As[ac + 3][ar] = make_float2(v23.z, v23.w);
    const float4* srcb = (const float4*)(Xb + (size_t)(k0 + bk) * kL + n0 + bc);
    ((float4*)&Bs[bk][bc])[0] = srcb[0];
    ((float4*)&Bs[bk][bc])[1] = srcb[1];
    __syncthreads();
#pragma unroll
    for (int kk = 0; kk < 16; ++kk) {
      const float4* arow = (const float4*)&As[kk][0];
      float4 a01 = arow[tm * 2 + 0], a23 = arow[tm * 2 + 1];
      float2 a[4] = {make_float2(a01.x, a01.y), make_float2(a01.z, a01.w),
                     make_float2(a23.x, a23.y), make_float2(a23.z, a23.w)};
      const float4* brow = (const float4*)&Bs[kk][0];
      float4 b01 = brow[tn * 2 + 0], b23 = brow[tn * 2 + 1];
      float2 bbv[4] = {make_float2(b01.x, b01.y), make_float2(b01.z, b01.w),
                       make_float2(b23.x, b23.y), make_float2(b23.z, b23.w)};
#pragma unroll
      for (int mi = 0; mi < 4; mi++)
#pragma unroll
        for (int ni = 0; ni < 4; ni++) {
          acc[mi][ni] = fmaf(a[mi].x, bbv[ni].x, acc[mi][ni]);
          acc[mi][ni] = fmaf(-a[mi].y, bbv[ni].y, acc[mi][ni]);
        }
    }
    __syncthreads();
  }
#pragma unroll
  for (int mi = 0; mi < 4; mi++) {
    int h = m0 + tm * 4 + mi;
    float d = D[h];
    const float* urow = u + ((size_t)b * kH + h) * kL + n0 + tn * 4;
    float4 uv = *(const float4*)urow;
    float uu[4] = {uv.x, uv.y, uv.z, uv.w};
    float res[4];
#pragma unroll
    for (int ni = 0; ni < 4; ni++) {
      float y = 2.f * acc[mi][ni] + d * uu[ni];
      res[ni] = 0.5f * y * (1.f + erff(y * 0.70710678118654752f));
    }
    float* orow = out + ((size_t)b * kH + h) * kL + n0 + tn * 4;
    *(float4*)orow = make_float4(res[0], res[1], res[2], res[3]);
  }
}

// ---------------------------------------------------------------- launch
extern "C" void kernel_launch(void* const* d_in, const int* in_sizes, int n_in,
                              void* d_out, int out_size, void* d_ws, size_t ws_size,
                              hipStream_t stream) {
  const float* input_sequence = (const float*)d_in[0];
  const float* Lambda_re = (const float*)d_in[2];
  const float* Lambda_im = (const float*)d_in[3];
  const float* B = (const float*)d_in[4];
  const float* C = (const float*)d_in[5];
  const float* D = (const float*)d_in[6];
  const float* log_step = (const float*)d_in[7];
  float* out = (float*)d_out;

  if (ws_size >= MID_BYTES) {
    unsigned char* ws = (unsigned char*)d_ws;
    unsigned short* a1h = (unsigned short*)(ws + A1H_OFF);
    unsigned short* a2h = (unsigned short*)(ws + A2H_OFF);
    float2* lbar = (float2*)(ws + LBAR_B);
    float* bu = (float*)(ws + BU_B);
    unsigned short* th = (unsigned short*)(ws + TH_B);
    // buffer reuse after scan: xs bf16 planar -> th region; its transpose ->
    // bu region (fp32 bu dead after scan)
    unsigned short* xsh = th;
    unsigned short* xshT = (unsigned short*)(ws + BU_B);

    k_prep12<<<dim3(kP + kH), 256, 0, stream>>>(Lambda_re, Lambda_im, B,
                                                log_step, C, ws);

    dim3 tgrid(kL / 64, 1024 / 64, kB);
    dim3 ggrid(kN / 256, kM / 128, kB);  // 16 x 8 x 4 = 512 blocks

    k_transpose<<<tgrid, 256, 0, stream>>>(input_sequence, th);
    k_gemm2p<false><<<ggrid, 512, 0, stream>>>(a1h, th, bu, nullptr, nullptr);
    k_scan<<<dim3(kB * kP), 256, 0, stream>>>(bu, lbar, xsh);
    k_transpose_h<<<tgrid, 256, 0, stream>>>(xsh, xshT);
    k_gemm2p<true><<<ggrid, 512, 0, stream>>>(a2h, xshT, out, input_sequence, D);
  } else {
    // fp32 fallback (round-1 path)
    float2* ws = (float2*)d_ws;
    float2* Bbar = ws + OBBAR;
    float2* Lbar = ws + OLBAR;
    float2* Bu = ws + OBU;
    k_precomputeF<<<dim3(kP), 256, 0, stream>>>(Lambda_re, Lambda_im, B, log_step, ws);
    k_gemm1F<<<dim3(kL / 64, kP / 64, kB), 256, 0, stream>>>(Bbar, input_sequence, Bu);
    k_scanF<<<dim3(kB * kP), 256, 0, stream>>>(Bu, Lbar);
    k_gemm2F<<<dim3(kL / 64, kH / 64, kB), 256, 0, stream>>>(
        (const float2*)C, (const float2*)Bu, input_sequence, D, out);
  }
}

// Round 9
// 248.831 us; speedup vs baseline: 1.2761x; 1.0958x over previous
//
#include <hip/hip_runtime.h>
#include <math.h>

// S5 SSM forward — R13: dispatch-count + traffic cuts; GEMM schedule frozen.
// R12 calibration: streaming ~5 TB/s, ~14us overhead per dispatch -> levers
// are dispatch count and bytes, not the GEMM (65-67us floor, 4 variants).
// This round:
//  1. prep12 merged INTO transpose1 (independent work, one dispatch saved).
//  2. GEMM1 writes Bu as bf16 planar (32 MB not 64); scan reads bf16,
//     computes fp32, writes bf16 xs (as R12). Scan amplifies Bu noise and
//     signal equally -> adds ~1 bf16 ULP relative on xs, same order as the
//     rounding xs already gets. Pre-commit: if accuracy fails, revert #2.
// BSZ=4, L=4096, H=1024, P=512.

constexpr int kB = 4, kL = 4096, kH = 1024, kP = 512;
constexpr int kM = 1024, kK = 1024, kN = 4096;

typedef short bf16x8 __attribute__((ext_vector_type(8)));
typedef float f32x4 __attribute__((ext_vector_type(4)));

// ---- ws layout (bytes), MFMA path
constexpr size_t A1H_OFF = 0;                                    // 2 MiB
constexpr size_t A2H_OFF = A1H_OFF + (size_t)kM * kK * 2;        // 2 MiB
constexpr size_t LBAR_B  = A2H_OFF + (size_t)kM * kK * 2;        // 4 KiB
constexpr size_t BU_B    = (LBAR_B + 4096 + 255) & ~(size_t)255; // 64 MiB region
constexpr size_t TH_B    = BU_B + (size_t)kB * kM * kN * 4;      // 32 MiB bf16
constexpr size_t MID_BYTES = TH_B + (size_t)kB * kN * kK * 2;    // ~100 MiB

// ---- bf16 helpers
__device__ __forceinline__ unsigned short f2bf(float x) {
  unsigned int u = __float_as_uint(x);
  u += 0x7fffu + ((u >> 16) & 1u);
  return (unsigned short)(u >> 16);
}
__device__ __forceinline__ float bf2f(unsigned short h) {
  return __uint_as_float(((unsigned int)h) << 16);
}

__device__ __forceinline__ void gl2lds16(const void* g, void* l) {
  __builtin_amdgcn_global_load_lds(
      (const __attribute__((address_space(1))) void*)g,
      (__attribute__((address_space(3))) void*)l, 16, 0, 0);
}

// s_waitcnt with vmcnt=N, lgkmcnt/expcnt = don't-care
template <int N>
__device__ __forceinline__ void wait_vm() {
  __builtin_amdgcn_s_waitcnt((N & 15) | ((N >> 4) << 14) | (15 << 8) | (7 << 4));
}

// ---------------------------------------------------------------- prep + transpose1 (merged)
// blocks 0..4095: fp32->bf16T transpose of u  [replay-proven body]
// blocks 4096..4607: prep1 (p = bid-4096); 4608..5631: prep2 (h = bid-4608)
__global__ __launch_bounds__(256) void k_prep_tr(
    const float* __restrict__ Lre, const float* __restrict__ Lim,
    const float* __restrict__ B, const float* __restrict__ log_step,
    const float* __restrict__ C, unsigned char* __restrict__ ws,
    const float* __restrict__ in, unsigned short* __restrict__ oh) {
  int bid = blockIdx.x;
  if (bid < 4096) {
    __shared__ float t[64][65];
    int b = bid >> 10;
    int r0 = ((bid >> 6) & 15) * 64;
    int c0 = (bid & 63) * 64;
    int tid = threadIdx.x;
    const float* src = in + ((size_t)b * 1024 + r0) * 4096 + c0;
    int cc = (tid & 15) * 4, rr = tid >> 4;
#pragma unroll
    for (int i = 0; i < 4; i++) {
      float4 v = *(const float4*)(src + (size_t)(rr + i * 16) * 4096 + cc);
      t[rr + i * 16][cc + 0] = v.x;
      t[rr + i * 16][cc + 1] = v.y;
      t[rr + i * 16][cc + 2] = v.z;
      t[rr + i * 16][cc + 3] = v.w;
    }
    __syncthreads();
    int oc = tid >> 2;
    int og = (tid & 3) * 2;
#pragma unroll
    for (int i = 0; i < 2; i++) {
      int g = og + i;
      unsigned short hv[8];
#pragma unroll
      for (int j = 0; j < 8; j++) hv[j] = f2bf(t[g * 8 + j][oc]);
      size_t ob = ((size_t)b * 4096 + c0 + oc) * 1024 + r0 + g * 8;
      *(uint4*)(oh + ob) = *(uint4*)hv;
    }
  } else if (bid < 4096 + kP) {
    int p = bid - 4096;
    float lr = Lre[p], li = Lim[p];
    float step = expf(log_step[p]);
    float er = expf(lr * step);
    float sb, cb;
    sincosf(li * step, &sb, &cb);
    float lbr = er * cb, lbi = er * sb;
    float nr = lbr - 1.0f, ni = lbi;
    float inv = 1.0f / (lr * lr + li * li);
    float sr = (nr * lr + ni * li) * inv;
    float si = (ni * lr - nr * li) * inv;

    if (threadIdx.x == 0) ((float2*)(ws + LBAR_B))[p] = make_float2(lbr, lbi);

    unsigned short* a1h = (unsigned short*)(ws + A1H_OFF);
    const float* Brow = B + (size_t)p * kH * 2;
    for (int h = threadIdx.x; h < kH; h += 256) {
      float br = Brow[2 * h], bi = Brow[2 * h + 1];
      a1h[(size_t)p * kK + h] = f2bf(sr * br - si * bi);
      a1h[(size_t)(kP + p) * kK + h] = f2bf(sr * bi + si * br);
    }
  } else {
    int h = bid - 4096 - kP;
    unsigned short* a2h = (unsigned short*)(ws + A2H_OFF);
    for (int k = threadIdx.x; k < kK; k += 256) {
      float v = (k < kP) ? 2.f * C[((size_t)h * kP + k) * 2]
                         : -2.f * C[((size_t)h * kP + (k - kP)) * 2 + 1];
      a2h[(size_t)h * kK + k] = f2bf(v);
    }
  }
}

// ---------------------------------------------------------------- transpose (bf16 -> bf16T)
// in: bf16 [b][1024][4096] -> out: bf16 [b][4096][1024]   [R12-proven]
__global__ __launch_bounds__(256) void k_transpose_h(
    const unsigned short* __restrict__ in, unsigned short* __restrict__ oh) {
  __shared__ float t[64][65];
  int b = blockIdx.z;
  int r0 = blockIdx.y * 64;
  int c0 = blockIdx.x * 64;
  int tid = threadIdx.x;
  const unsigned short* src = in + ((size_t)b * 1024 + r0) * 4096 + c0;
  int cc = (tid & 7) * 8, rr = tid >> 3;  // rr 0..31
#pragma unroll
  for (int i = 0; i < 2; i++) {
    bf16x8 v = *(const bf16x8*)(src + (size_t)(rr + i * 32) * 4096 + cc);
#pragma unroll
    for (int j = 0; j < 8; j++)
      t[rr + i * 32][cc + j] = bf2f((unsigned short)v[j]);
  }
  __syncthreads();
  int oc = tid >> 2;
  int og = (tid & 3) * 2;
#pragma unroll
  for (int i = 0; i < 2; i++) {
    int g = og + i;
    unsigned short hv[8];
#pragma unroll
    for (int j = 0; j < 8; j++) hv[j] = f2bf(t[g * 8 + j][oc]);
    size_t ob = ((size_t)b * 4096 + c0 + oc) * 1024 + r0 + g * 8;
    *(uint4*)(oh + ob) = *(uint4*)hv;
  }
}

// ================================================================ 2-phase GEMM
// R9 verbatim schedule (measured floor 65-67us): 128x256 tile, BK=32, 8 waves,
// 48 KiB LDS (2 bufs), st_16x32 swizzle, gl_lds linear-dest + inv-swz source,
// 1 barrier + 1 vmcnt(0) per K-tile.
// EPI=false: out is bf16 (Bu planar). EPI=true: out fp32 with D*u + GeLU.

__device__ __forceinline__ int stage_src_off32(int Dp) {
  int Ds = Dp ^ (((Dp >> 9) & 1) << 5);  // involution
  int s = Ds >> 10, d = Ds & 1023;       // subtile (row-block), within-subtile
  int row = (s << 4) + (d >> 6);         // 0..127
  int kk = (d & 63) >> 1;                // 0..31 (multiple of 8)
  return row * kK + kk;
}

#define BAR __builtin_amdgcn_s_barrier()
#define LGKM0                                           \
  do {                                                  \
    asm volatile("s_waitcnt lgkmcnt(0)" ::: "memory");  \
    __builtin_amdgcn_sched_barrier(0);                  \
  } while (0)

template <bool EPI>
__global__ __launch_bounds__(512, 4) void k_gemm2p(
    const unsigned short* __restrict__ Ah, const unsigned short* __restrict__ Bh,
    void* __restrict__ outv, const float* __restrict__ u,
    const float* __restrict__ D) {
  __shared__ __align__(16) unsigned char lds[49152];
  constexpr int BUF = 24576;
  constexpr int NKT = kK / 32;  // 32 K-tiles

  int b = blockIdx.z;
  int m0 = blockIdx.y * 128, n0 = blockIdx.x * 256;
  int tid = threadIdx.x, w = tid >> 6;
  int q = (tid >> 4) & 3, r = tid & 15;
  int wm = (w >> 2) * 64, wn = (w & 3) * 64;
  int wmrb = (w >> 2) * 4, wnrb = (w & 3) * 4;
  int lane_off = (r * 64 + q * 16) ^ ((r & 8) << 2);  // st_16x32 read swizzle

  int d0 = tid << 4;
  int rowk = stage_src_off32(d0);  // same decode for A piece and each B half

  const unsigned short* pA = Ah + (size_t)m0 * kK;
  const unsigned short* pB = Bh + (size_t)b * kN * kK + (size_t)n0 * kK;

  f32x4 acc[4][4] = {};

  // one K-tile stage: A 8KB (rows 0-127) + B 16KB (two 8KB halves)
#define STG(KT, LB)                                                       \
  do {                                                                    \
    gl2lds16(pA + (KT) * 32 + rowk, lds + (LB) + d0);                     \
    gl2lds16(pB + (KT) * 32 + rowk, lds + (LB) + 8192 + d0);              \
    gl2lds16(pB + (size_t)128 * kK + (KT) * 32 + rowk,                    \
             lds + (LB) + 16384 + d0);                                    \
  } while (0)

  // one K-tile compute: 4 A-frags + 4 B-frags -> 16 MFMA into acc
#define COMPUTE(LB)                                                       \
  do {                                                                    \
    bf16x8 a[4], bb[4];                                                   \
    _Pragma("unroll")                                                     \
    for (int mi = 0; mi < 4; mi++)                                        \
      a[mi] = *(const bf16x8*)(lds + (LB) + ((wmrb + mi) << 10) + lane_off); \
    _Pragma("unroll")                                                     \
    for (int nj = 0; nj < 4; nj++)                                        \
      bb[nj] = *(const bf16x8*)(lds + (LB) + 8192 +                       \
                                ((wnrb + nj) << 10) + lane_off);          \
    LGKM0;                                                                \
    __builtin_amdgcn_s_setprio(1);                                        \
    _Pragma("unroll")                                                     \
    for (int mi = 0; mi < 4; mi++)                                        \
      _Pragma("unroll")                                                   \
      for (int nj = 0; nj < 4; nj++)                                      \
        acc[mi][nj] = __builtin_amdgcn_mfma_f32_16x16x32_bf16(            \
            a[mi], bb[nj], acc[mi][nj], 0, 0, 0);                         \
    __builtin_amdgcn_s_setprio(0);                                        \
  } while (0)

  // prologue: buf0 <- kt0
  STG(0, 0);
  wait_vm<0>();
  BAR;

  for (int it = 0; it < NKT / 2; ++it) {
    int kt = it * 2;
    // phase A: stage buf1 <- kt+1; compute buf0 (kt)
    if (kt + 1 < NKT) STG(kt + 1, BUF);
    COMPUTE(0);
    wait_vm<0>();  // kt+1 loads landed (had full MFMA phase to fly)
    BAR;           // also fences: all reads of buf0 done -> safe to restage
    // phase B: stage buf0 <- kt+2; compute buf1 (kt+1)
    if (kt + 2 < NKT) STG(kt + 2, 0);
    COMPUTE(BUF);
    wait_vm<0>();
    BAR;
  }
#undef STG
#undef COMPUTE

  // C/D layout: col = r, row = q*4 + reg   [R8/R9-proven]
  float* outf = (float*)outv;
  unsigned short* outh = (unsigned short*)outv;
#pragma unroll
  for (int mi = 0; mi < 4; mi++) {
#pragma unroll
    for (int reg = 0; reg < 4; reg++) {
      int row = m0 + wm + mi * 16 + q * 4 + reg;
      float dv = EPI ? D[row] : 0.f;
#pragma unroll
      for (int ni = 0; ni < 4; ni++) {
        int col = n0 + wn + ni * 16 + r;
        size_t o = ((size_t)b * kM + row) * (size_t)kN + col;
        float v = acc[mi][ni][reg];
        if (EPI) {
          float y = v + dv * u[o];
          outf[o] = 0.5f * y * (1.f + erff(y * 0.70710678118654752f));
        } else {
          outh[o] = f2bf(v);
        }
      }
    }
  }
}

// ---------------------------------------------------------------- scan
// bf16 planar in (buh), fp32 internal, bf16 planar out (xsh).
__global__ __launch_bounds__(256) void k_scan(
    const unsigned short* __restrict__ buh, const float2* __restrict__ lbar,
    unsigned short* __restrict__ xsh) {
  int p = blockIdx.x & (kP - 1);
  int b = blockIdx.x >> 9;
  int tid = threadIdx.x, lane = tid & 63, w = tid >> 6;
  float2 lam = lbar[p];
  const unsigned short* sre = buh + ((size_t)b * kM + p) * (size_t)kN;
  const unsigned short* sim = sre + (size_t)kP * kN;

  float vr[16], vi[16];
  {
    const bf16x8* pr = (const bf16x8*)(sre + tid * 16);
    const bf16x8* pi = (const bf16x8*)(sim + tid * 16);
#pragma unroll
    for (int i = 0; i < 2; i++) {
      bf16x8 a = pr[i], c = pi[i];
#pragma unroll
      for (int j = 0; j < 8; j++) {
        vr[8 * i + j] = bf2f((unsigned short)a[j]);
        vi[8 * i + j] = bf2f((unsigned short)c[j]);
      }
    }
  }

  float xr = 0.f, xi = 0.f;
#pragma unroll
  for (int i = 0; i < 16; i++) {
    float nr2 = fmaf(lam.x, xr, fmaf(-lam.y, xi, vr[i]));
    float ni2 = fmaf(lam.x, xi, fmaf(lam.y, xr, vi[i]));
    xr = nr2; xi = ni2;
  }

  float Ar = lam.x, Ai = lam.y;
#pragma unroll
  for (int s = 0; s < 4; s++) {
    float tr = Ar * Ar - Ai * Ai, ti = 2.f * Ar * Ai;
    Ar = tr; Ai = ti;
  }
  float br = xr, bi = xi;

  for (int off = 1; off < 64; off <<= 1) {
    float pAr = __shfl_up(Ar, off), pAi = __shfl_up(Ai, off);
    float pbr = __shfl_up(br, off), pbi = __shfl_up(bi, off);
    if (lane >= off) {
      float nAr = Ar * pAr - Ai * pAi;
      float nAi = Ar * pAi + Ai * pAr;
      float nbr = Ar * pbr - Ai * pbi + br;
      float nbi = Ar * pbi + Ai * pbr + bi;
      Ar = nAr; Ai = nAi; br = nbr; bi = nbi;
    }
  }

  __shared__ float4 wtot[4];
  if (lane == 63) wtot[w] = make_float4(Ar, Ai, br, bi);
  __syncthreads();

  float eAr = __shfl_up(Ar, 1), eAi = __shfl_up(Ai, 1);
  float ebr = __shfl_up(br, 1), ebi = __shfl_up(bi, 1);
  if (lane == 0) { eAr = 1.f; eAi = 0.f; ebr = 0.f; ebi = 0.f; }

  float pAr = 1.f, pAi = 0.f, pbr = 0.f, pbi = 0.f;
  for (int j = 0; j < w; j++) {
    float4 t = wtot[j];
    float nAr = t.x * pAr - t.y * pAi;
    float nAi = t.x * pAi + t.y * pAr;
    float nbr = t.x * pbr - t.y * pbi + t.z;
    float nbi = t.x * pbi + t.y * pbr + t.w;
    pAr = nAr; pAi = nAi; pbr = nbr; pbi = nbi;
  }

  float initr = eAr * pbr - eAi * pbi + ebr;
  float initi = eAr * pbi + eAi * pbr + ebi;

  xr = initr; xi = initi;
  __align__(16) unsigned short hr[16], him[16];
#pragma unroll
  for (int i = 0; i < 16; i++) {
    float nr2 = fmaf(lam.x, xr, fmaf(-lam.y, xi, vr[i]));
    float ni2 = fmaf(lam.x, xi, fmaf(lam.y, xr, vi[i]));
    xr = nr2; xi = ni2;
    hr[i] = f2bf(nr2); him[i] = f2bf(ni2);
  }
  unsigned short* drh = xsh + ((size_t)b * kM + p) * (size_t)kN + tid * 16;
  unsigned short* dih = drh + (size_t)kP * kN;
  ((uint4*)drh)[0] = *(uint4*)&hr[0];
  ((uint4*)drh)[1] = *(uint4*)&hr[8];
  ((uint4*)dih)[0] = *(uint4*)&him[0];
  ((uint4*)dih)[1] = *(uint4*)&him[8];
}

// ================================================================ fp32 fallback
constexpr size_t OBBAR = 0;
constexpr size_t OLBAR = (size_t)kP * kH;
constexpr size_t OBU = OLBAR + 1024;

__global__ __launch_bounds__(256) void k_precomputeF(
    const float* __restrict__ Lre, const float* __restrict__ Lim,
    const float* __restrict__ B, const float* __restrict__ log_step,
    float2* __restrict__ ws) {
  int p = blockIdx.x;
  float lr = Lre[p], li = Lim[p];
  float step = expf(log_step[p]);
  float er = expf(lr * step);
  float sb, cb;
  sincosf(li * step, &sb, &cb);
  float lbr = er * cb, lbi = er * sb;
  float nr = lbr - 1.0f, ni = lbi;
  float inv = 1.0f / (lr * lr + li * li);
  float sr = (nr * lr + ni * li) * inv;
  float si = (ni * lr - nr * li) * inv;
  if (threadIdx.x == 0) ws[OLBAR + p] = make_float2(lbr, lbi);
  float2* Bbar = ws + OBBAR;
  const float* Brow = B + (size_t)p * kH * 2;
  for (int h = threadIdx.x; h < kH; h += 256) {
    float br = Brow[2 * h], bi = Brow[2 * h + 1];
    Bbar[(size_t)p * kH + h] = make_float2(sr * br - si * bi, sr * bi + si * br);
  }
}

__global__ __launch_bounds__(256) void k_gemm1F(
    const float2* __restrict__ ws_bbar, const float* __restrict__ u,
    float2* __restrict__ Bu) {
  __shared__ float2 As[16][64];
  __shared__ float Bs[16][64];
  int b = blockIdx.z, m0 = blockIdx.y * 64, n0 = blockIdx.x * 64;
  int tid = threadIdx.x, tn = tid & 15, tm = tid >> 4;
  const float* uB = u + (size_t)b * kH * kL;
  float2 acc[4][4];
#pragma unroll
  for (int i = 0; i < 4; i++)
#pragma unroll
    for (int j = 0; j < 4; j++) acc[i][j] = make_float2(0.f, 0.f);
  int ar = tid >> 2, ac = (tid & 3) * 4, bk = tid >> 4, bc = (tid & 15) * 4;
  for (int k0 = 0; k0 < kH; k0 += 16) {
    const float4* src = (const float4*)(ws_bbar + (size_t)(m0 + ar) * kH + k0 + ac);
    float4 v01 = src[0], v23 = src[1];
    As[ac + 0][ar] = make_float2(v01.x, v01.y);
    As[ac + 1][ar] = make_float2(v01.z, v01.w);
    As[ac + 2][ar] = make_float2(v23.x, v23.y);
    As[ac + 3][ar] = make_float2(v23.z, v23.w);
    float4 v = *(const float4*)(uB + (size_t)(k0 + bk) * kL + n0 + bc);
    *(float4*)&Bs[bk][bc] = v;
    __syncthreads();
#pragma unroll
    for (int kk = 0; kk < 16; ++kk) {
      const float4* arow = (const float4*)&As[kk][0];
      float4 a01 = arow[tm * 2 + 0], a23 = arow[tm * 2 + 1];
      float2 a[4] = {make_float2(a01.x, a01.y), make_float2(a01.z, a01.w),
                     make_float2(a23.x, a23.y), make_float2(a23.z, a23.w)};
      float4 bv = ((const float4*)&Bs[kk][0])[tn];
      float bbv[4] = {bv.x, bv.y, bv.z, bv.w};
#pragma unroll
      for (int mi = 0; mi < 4; mi++)
#pragma unroll
        for (int ni = 0; ni < 4; ni++) {
          acc[mi][ni].x = fmaf(a[mi].x, bbv[ni], acc[mi][ni].x);
          acc[mi][ni].y = fmaf(a[mi].y, bbv[ni], acc[mi][ni].y);
        }
    }
    __syncthreads();
  }
  float2* BuB = Bu + (size_t)b * kP * kL;
#pragma unroll
  for (int mi = 0; mi < 4; mi++) {
    int row = m0 + tm * 4 + mi;
    float2* dst = BuB + (size_t)row * kL + n0 + tn * 4;
    ((float4*)dst)[0] = make_float4(acc[mi][0].x, acc[mi][0].y, acc[mi][1].x, acc[mi][1].y);
    ((float4*)dst)[1] = make_float4(acc[mi][2].x, acc[mi][2].y, acc[mi][3].x, acc[mi][3].y);
  }
}

__global__ __launch_bounds__(256) void k_scanF(float2* __restrict__ Bu,
                                               const float2* __restrict__ Lbar) {
  int p = blockIdx.x & (kP - 1);
  int b = blockIdx.x >> 9;
  int tid = threadIdx.x, lane = tid & 63, w = tid >> 6;
  float2 lam = Lbar[p];
  float2* seq = Bu + ((size_t)b * kP + p) * kL;
  float2 v[16];
  const float4* src = (const float4*)(seq + tid * 16);
#pragma unroll
  for (int i = 0; i < 8; i++) {
    float4 t = src[i];
    v[2 * i] = make_float2(t.x, t.y);
    v[2 * i + 1] = make_float2(t.z, t.w);
  }
  float xr = 0.f, xi = 0.f;
#pragma unroll
  for (int i = 0; i < 16; i++) {
    float nr2 = fmaf(lam.x, xr, fmaf(-lam.y, xi, v[i].x));
    float ni2 = fmaf(lam.x, xi, fmaf(lam.y, xr, v[i].y));
    xr = nr2; xi = ni2;
  }
  float Ar = lam.x, Ai = lam.y;
#pragma unroll
  for (int s = 0; s < 4; s++) {
    float tr = Ar * Ar - Ai * Ai, ti = 2.f * Ar * Ai;
    Ar = tr; Ai = ti;
  }
  float br = xr, bi = xi;
  for (int off = 1; off < 64; off <<= 1) {
    float pAr = __shfl_up(Ar, off), pAi = __shfl_up(Ai, off);
    float pbr = __shfl_up(br, off), pbi = __shfl_up(bi, off);
    if (lane >= off) {
      float nAr = Ar * pAr - Ai * pAi, nAi = Ar * pAi + Ai * pAr;
      float nbr = Ar * pbr - Ai * pbi + br, nbi = Ar * pbi + Ai * pbr + bi;
      Ar = nAr; Ai = nAi; br = nbr; bi = nbi;
    }
  }
  __shared__ float4 wtot[4];
  if (lane == 63) wtot[w] = make_float4(Ar, Ai, br, bi);
  __syncthreads();
  float eAr = __shfl_up(Ar, 1), eAi = __shfl_up(Ai, 1);
  float ebr = __shfl_up(br, 1), ebi = __shfl_up(bi, 1);
  if (lane == 0) { eAr = 1.f; eAi = 0.f; ebr = 0.f; ebi = 0.f; }
  float pAr = 1.f, pAi = 0.f, pbr = 0.f, pbi = 0.f;
  for (int j = 0; j < w; j++) {
    float4 t = wtot[j];
    float nAr = t.x * pAr - t.y * pAi, nAi = t.x * pAi + t.y * pAr;
    float nbr = t.x * pbr - t.y * pbi + t.z, nbi = t.x * pbi + t.y * pbr + t.w;
    pAr = nAr; pAi = nAi; pbr = nbr; pbi = nbi;
  }
  float initr = eAr * pbr - eAi * pbi + ebr;
  float initi = eAr * pbi + eAi * pbr + ebi;
  xr = initr; xi = initi;
  float4* dst = (float4*)(seq + tid * 16);
#pragma unroll
  for (int i = 0; i < 8; i++) {
    float nr0 = fmaf(lam.x, xr, fmaf(-lam.y, xi, v[2 * i].x));
    float ni0 = fmaf(lam.x, xi, fmaf(lam.y, xr, v[2 * i].y));
    float nr1 = fmaf(lam.x, nr0, fmaf(-lam.y, ni0, v[2 * i + 1].x));
    float ni1 = fmaf(lam.x, ni0, fmaf(lam.y, nr0, v[2 * i + 1].y));
    dst[i] = make_float4(nr0, ni0, nr1, ni1);
    xr = nr1; xi = ni1;
  }
}

__global__ __launch_bounds__(256) void k_gemm2F(
    const float2* __restrict__ C, const float2* __restrict__ X,
    const float* __restrict__ u, const float* __restrict__ D,
    float* __restrict__ out) {
  __shared__ float2 As[16][64];
  __shared__ float2 Bs[16][64];
  int b = blockIdx.z, m0 = blockIdx.y * 64, n0 = blockIdx.x * 64;
  int tid = threadIdx.x, tn = tid & 15, tm = tid >> 4;
  const float2* Xb = X + (size_t)b * kP * kL;
  float acc[4][4];
#pragma unroll
  for (int i = 0; i < 4; i++)
#pragma unroll
    for (int j = 0; j < 4; j++) acc[i][j] = 0.f;
  int ar = tid >> 2, ac = (tid & 3) * 4, bk = tid >> 4, bc = (tid & 15) * 4;
  for (int k0 = 0; k0 < kP; k0 += 16) {
    const float4* src = (const float4*)(C + (size_t)(m0 + ar) * kP + k0 + ac);
    float4 v01 = src[0], v23 = src[1];
    As[ac + 0][ar] = make_float2(v01.x, v01.y);
    As[ac + 1][ar] = make_float2(v01.z, v01.w);
    As[ac + 2][ar] = make_float2(v23.x, v23.y);
    As[ac + 3][ar] = make_float2(v23.z, v23.w);
    const float4* srcb = (const float4*)(Xb + (size_t)(k0 + bk) * kL + n0 + bc);
    ((float4*)&Bs[bk][bc])[0] = srcb[0];
    ((float4*)&Bs[bk][bc])[1] = srcb[1];
    __syncthreads();
#pragma unroll
    for (int kk = 0; kk < 16; ++kk) {
      const float4* arow = (const float4*)&As[kk][0];
      float4 a01 = arow[tm * 2 + 0], a23 = arow[tm * 2 + 1];
      float2 a[4] = {make_float2(a01.x, a01.y), make_float2(a01.z, a01.w),
                     make_float2(a23.x, a23.y), make_float2(a23.z, a23.w)};
      const float4* brow = (const float4*)&Bs[kk][0];
      float4 b01 = brow[tn * 2 + 0], b23 = brow[tn * 2 + 1];
      float2 bbv[4] = {make_float2(b01.x, b01.y), make_float2(b01.z, b01.w),
                       make_float2(b23.x, b23.y), make_float2(b23.z, b23.w)};
#pragma unroll
      for (int mi = 0; mi < 4; mi++)
#pragma unroll
        for (int ni = 0; ni < 4; ni++) {
          acc[mi][ni] = fmaf(a[mi].x, bbv[ni].x, acc[mi][ni]);
          acc[mi][ni] = fmaf(-a[mi].y, bbv[ni].y, acc[mi][ni]);
        }
    }
    __syncthreads();
  }
#pragma unroll
  for (int mi = 0; mi < 4; mi++) {
    int h = m0 + tm * 4 + mi;
    float d = D[h];
    const float* urow = u + ((size_t)b * kH + h) * kL + n0 + tn * 4;
    float4 uv = *(const float4*)urow;
    float uu[4] = {uv.x, uv.y, uv.z, uv.w};
    float res[4];
#pragma unroll
    for (int ni = 0; ni < 4; ni++) {
      float y = 2.f * acc[mi][ni] + d * uu[ni];
      res[ni] = 0.5f * y * (1.f + erff(y * 0.70710678118654752f));
    }
    float* orow = out + ((size_t)b * kH + h) * kL + n0 + tn * 4;
    *(float4*)orow = make_float4(res[0], res[1], res[2], res[3]);
  }
}

// ---------------------------------------------------------------- launch
extern "C" void kernel_launch(void* const* d_in, const int* in_sizes, int n_in,
                              void* d_out, int out_size, void* d_ws, size_t ws_size,
                              hipStream_t stream) {
  const float* input_sequence = (const float*)d_in[0];
  const float* Lambda_re = (const float*)d_in[2];
  const float* Lambda_im = (const float*)d_in[3];
  const float* B = (const float*)d_in[4];
  const float* C = (const float*)d_in[5];
  const float* D = (const float*)d_in[6];
  const float* log_step = (const float*)d_in[7];
  float* out = (float*)d_out;

  if (ws_size >= MID_BYTES) {
    unsigned char* ws = (unsigned char*)d_ws;
    unsigned short* a1h = (unsigned short*)(ws + A1H_OFF);
    unsigned short* a2h = (unsigned short*)(ws + A2H_OFF);
    float2* lbar = (float2*)(ws + LBAR_B);
    unsigned short* th = (unsigned short*)(ws + TH_B);    // uT bf16
    unsigned short* buh = (unsigned short*)(ws + BU_B);   // Bu bf16 planar (32MB)
    unsigned short* xsh = th;                             // xs bf16 planar (uT dead)
    unsigned short* xshT = (unsigned short*)(ws + BU_B);  // xs^T (buh dead)

    // 1: prep + transpose1 (merged)
    k_prep_tr<<<dim3(4096 + kP + kH), 256, 0, stream>>>(
        Lambda_re, Lambda_im, B, log_step, C, ws, input_sequence, th);

    dim3 tgrid(kL / 64, 1024 / 64, kB);
    dim3 ggrid(kN / 256, kM / 128, kB);  // 16 x 8 x 4 = 512 blocks

    // 2: GEMM1 -> Bu bf16 planar
    k_gemm2p<false><<<ggrid, 512, 0, stream>>>(a1h, th, buh, nullptr, nullptr);
    // 3: scan (bf16 in, fp32 internal, bf16 out)
    k_scan<<<dim3(kB * kP), 256, 0, stream>>>(buh, lbar, xsh);
    // 4: transpose xs -> [b][l][m]
    k_transpose_h<<<tgrid, 256, 0, stream>>>(xsh, xshT);
    // 5: GEMM2 + D*u + GeLU -> out fp32
    k_gemm2p<true><<<ggrid, 512, 0, stream>>>(a2h, xshT, out, input_sequence, D);
  } else {
    // fp32 fallback (round-1 path)
    float2* ws = (float2*)d_ws;
    float2* Bbar = ws + OBBAR;
    float2* Lbar = ws + OLBAR;
    float2* Bu = ws + OBU;
    k_precomputeF<<<dim3(kP), 256, 0, stream>>>(Lambda_re, Lambda_im, B, log_step, ws);
    k_gemm1F<<<dim3(kL / 64, kP / 64, kB), 256, 0, stream>>>(Bbar, input_sequence, Bu);
    k_scanF<<<dim3(kB * kP), 256, 0, stream>>>(Bu, Lbar);
    k_gemm2F<<<dim3(kL / 64, kH / 64, kB), 256, 0, stream>>>(
        (const float2*)C, (const float2*)Bu, input_sequence, D, out);
  }
}

// Round 10
// 245.593 us; speedup vs baseline: 1.2930x; 1.0132x over previous
//
#include <hip/hip_runtime.h>
#include <math.h>

// S5 SSM forward — R14: GEMM2 consumes xs PLANAR (transpose_h deleted).
// R13 post-mortem: ~15us/dispatch gap confirmed; dispatch count is the lever.
// GEMM2's B-tile (n=l, k=m) is staged from planar xs[m][l] via gl_lds into a
// k-transposed LDS layout whose 16B lane-windows stay globally contiguous:
//   off(m,l) = (l&15)*2 + (m>>3)*32 + (m&7)*128 + (l>>4)*1024
// Fragment reads: 8x ds_read_u16 per frag, per-lane base r*2+q*32, uniform
// immediates i*128+nj*1024. Banks = 8q + (r>>1): all 32 banks, lane-pairs
// broadcast -> conflict-free. Values bit-identical to R13 (absmax tripwire:
// must stay exactly 0.0625). GEMM1/scan/prep byte-identical to R13.
// BSZ=4, L=4096, H=1024, P=512.

constexpr int kB = 4, kL = 4096, kH = 1024, kP = 512;
constexpr int kM = 1024, kK = 1024, kN = 4096;

typedef short bf16x8 __attribute__((ext_vector_type(8)));
typedef float f32x4 __attribute__((ext_vector_type(4)));

// ---- ws layout (bytes), MFMA path
constexpr size_t A1H_OFF = 0;                                    // 2 MiB
constexpr size_t A2H_OFF = A1H_OFF + (size_t)kM * kK * 2;        // 2 MiB
constexpr size_t LBAR_B  = A2H_OFF + (size_t)kM * kK * 2;        // 4 KiB
constexpr size_t BU_B    = (LBAR_B + 4096 + 255) & ~(size_t)255; // 64 MiB region
constexpr size_t TH_B    = BU_B + (size_t)kB * kM * kN * 4;      // 32 MiB bf16
constexpr size_t MID_BYTES = TH_B + (size_t)kB * kN * kK * 2;    // ~100 MiB

// ---- bf16 helpers
__device__ __forceinline__ unsigned short f2bf(float x) {
  unsigned int u = __float_as_uint(x);
  u += 0x7fffu + ((u >> 16) & 1u);
  return (unsigned short)(u >> 16);
}
__device__ __forceinline__ float bf2f(unsigned short h) {
  return __uint_as_float(((unsigned int)h) << 16);
}

__device__ __forceinline__ void gl2lds16(const void* g, void* l) {
  __builtin_amdgcn_global_load_lds(
      (const __attribute__((address_space(1))) void*)g,
      (__attribute__((address_space(3))) void*)l, 16, 0, 0);
}

// s_waitcnt with vmcnt=N, lgkmcnt/expcnt = don't-care
template <int N>
__device__ __forceinline__ void wait_vm() {
  __builtin_amdgcn_s_waitcnt((N & 15) | ((N >> 4) << 14) | (15 << 8) | (7 << 4));
}

// ---------------------------------------------------------------- prep + transpose1 (merged)
// blocks 0..4095: fp32->bf16T transpose of u  [replay-proven body]
// blocks 4096..4607: prep1 (p = bid-4096); 4608..5631: prep2 (h = bid-4608)
__global__ __launch_bounds__(256) void k_prep_tr(
    const float* __restrict__ Lre, const float* __restrict__ Lim,
    const float* __restrict__ B, const float* __restrict__ log_step,
    const float* __restrict__ C, unsigned char* __restrict__ ws,
    const float* __restrict__ in, unsigned short* __restrict__ oh) {
  int bid = blockIdx.x;
  if (bid < 4096) {
    __shared__ float t[64][65];
    int b = bid >> 10;
    int r0 = ((bid >> 6) & 15) * 64;
    int c0 = (bid & 63) * 64;
    int tid = threadIdx.x;
    const float* src = in + ((size_t)b * 1024 + r0) * 4096 + c0;
    int cc = (tid & 15) * 4, rr = tid >> 4;
#pragma unroll
    for (int i = 0; i < 4; i++) {
      float4 v = *(const float4*)(src + (size_t)(rr + i * 16) * 4096 + cc);
      t[rr + i * 16][cc + 0] = v.x;
      t[rr + i * 16][cc + 1] = v.y;
      t[rr + i * 16][cc + 2] = v.z;
      t[rr + i * 16][cc + 3] = v.w;
    }
    __syncthreads();
    int oc = tid >> 2;
    int og = (tid & 3) * 2;
#pragma unroll
    for (int i = 0; i < 2; i++) {
      int g = og + i;
      unsigned short hv[8];
#pragma unroll
      for (int j = 0; j < 8; j++) hv[j] = f2bf(t[g * 8 + j][oc]);
      size_t ob = ((size_t)b * 4096 + c0 + oc) * 1024 + r0 + g * 8;
      *(uint4*)(oh + ob) = *(uint4*)hv;
    }
  } else if (bid < 4096 + kP) {
    int p = bid - 4096;
    float lr = Lre[p], li = Lim[p];
    float step = expf(log_step[p]);
    float er = expf(lr * step);
    float sb, cb;
    sincosf(li * step, &sb, &cb);
    float lbr = er * cb, lbi = er * sb;
    float nr = lbr - 1.0f, ni = lbi;
    float inv = 1.0f / (lr * lr + li * li);
    float sr = (nr * lr + ni * li) * inv;
    float si = (ni * lr - nr * li) * inv;

    if (threadIdx.x == 0) ((float2*)(ws + LBAR_B))[p] = make_float2(lbr, lbi);

    unsigned short* a1h = (unsigned short*)(ws + A1H_OFF);
    const float* Brow = B + (size_t)p * kH * 2;
    for (int h = threadIdx.x; h < kH; h += 256) {
      float br = Brow[2 * h], bi = Brow[2 * h + 1];
      a1h[(size_t)p * kK + h] = f2bf(sr * br - si * bi);
      a1h[(size_t)(kP + p) * kK + h] = f2bf(sr * bi + si * br);
    }
  } else {
    int h = bid - 4096 - kP;
    unsigned short* a2h = (unsigned short*)(ws + A2H_OFF);
    for (int k = threadIdx.x; k < kK; k += 256) {
      float v = (k < kP) ? 2.f * C[((size_t)h * kP + k) * 2]
                         : -2.f * C[((size_t)h * kP + (k - kP)) * 2 + 1];
      a2h[(size_t)h * kK + k] = f2bf(v);
    }
  }
}

// ================================================================ 2-phase GEMM (std B layout)
// R9 verbatim schedule: 128x256 tile, BK=32, 8 waves, 48 KiB LDS (2 bufs),
// st_16x32 swizzle, gl_lds linear-dest + inv-swz source, 1 barrier + 1
// vmcnt(0) per K-tile. EPI=false: out bf16 (Bu planar).

__device__ __forceinline__ int stage_src_off32(int Dp) {
  int Ds = Dp ^ (((Dp >> 9) & 1) << 5);  // involution
  int s = Ds >> 10, d = Ds & 1023;       // subtile (row-block), within-subtile
  int row = (s << 4) + (d >> 6);         // 0..127
  int kk = (d & 63) >> 1;                // 0..31 (multiple of 8)
  return row * kK + kk;
}

#define BAR __builtin_amdgcn_s_barrier()
#define LGKM0                                           \
  do {                                                  \
    asm volatile("s_waitcnt lgkmcnt(0)" ::: "memory");  \
    __builtin_amdgcn_sched_barrier(0);                  \
  } while (0)

template <bool EPI>
__global__ __launch_bounds__(512, 4) void k_gemm2p(
    const unsigned short* __restrict__ Ah, const unsigned short* __restrict__ Bh,
    void* __restrict__ outv, const float* __restrict__ u,
    const float* __restrict__ D) {
  __shared__ __align__(16) unsigned char lds[49152];
  constexpr int BUF = 24576;
  constexpr int NKT = kK / 32;  // 32 K-tiles

  int b = blockIdx.z;
  int m0 = blockIdx.y * 128, n0 = blockIdx.x * 256;
  int tid = threadIdx.x, w = tid >> 6;
  int q = (tid >> 4) & 3, r = tid & 15;
  int wm = (w >> 2) * 64, wn = (w & 3) * 64;
  int wmrb = (w >> 2) * 4, wnrb = (w & 3) * 4;
  int lane_off = (r * 64 + q * 16) ^ ((r & 8) << 2);  // st_16x32 read swizzle

  int d0 = tid << 4;
  int rowk = stage_src_off32(d0);

  const unsigned short* pA = Ah + (size_t)m0 * kK;
  const unsigned short* pB = Bh + (size_t)b * kN * kK + (size_t)n0 * kK;

  f32x4 acc[4][4] = {};

#define STG(KT, LB)                                                       \
  do {                                                                    \
    gl2lds16(pA + (KT) * 32 + rowk, lds + (LB) + d0);                     \
    gl2lds16(pB + (KT) * 32 + rowk, lds + (LB) + 8192 + d0);              \
    gl2lds16(pB + (size_t)128 * kK + (KT) * 32 + rowk,                    \
             lds + (LB) + 16384 + d0);                                    \
  } while (0)

#define COMPUTE(LB)                                                       \
  do {                                                                    \
    bf16x8 a[4], bb[4];                                                   \
    _Pragma("unroll")                                                     \
    for (int mi = 0; mi < 4; mi++)                                        \
      a[mi] = *(const bf16x8*)(lds + (LB) + ((wmrb + mi) << 10) + lane_off); \
    _Pragma("unroll")                                                     \
    for (int nj = 0; nj < 4; nj++)                                        \
      bb[nj] = *(const bf16x8*)(lds + (LB) + 8192 +                       \
                                ((wnrb + nj) << 10) + lane_off);          \
    LGKM0;                                                                \
    __builtin_amdgcn_s_setprio(1);                                        \
    _Pragma("unroll")                                                     \
    for (int mi = 0; mi < 4; mi++)                                        \
      _Pragma("unroll")                                                   \
      for (int nj = 0; nj < 4; nj++)                                      \
        acc[mi][nj] = __builtin_amdgcn_mfma_f32_16x16x32_bf16(            \
            a[mi], bb[nj], acc[mi][nj], 0, 0, 0);                         \
    __builtin_amdgcn_s_setprio(0);                                        \
  } while (0)

  STG(0, 0);
  wait_vm<0>();
  BAR;

  for (int it = 0; it < NKT / 2; ++it) {
    int kt = it * 2;
    if (kt + 1 < NKT) STG(kt + 1, BUF);
    COMPUTE(0);
    wait_vm<0>();
    BAR;
    if (kt + 2 < NKT) STG(kt + 2, 0);
    COMPUTE(BUF);
    wait_vm<0>();
    BAR;
  }
#undef STG
#undef COMPUTE

  float* outf = (float*)outv;
  unsigned short* outh = (unsigned short*)outv;
#pragma unroll
  for (int mi = 0; mi < 4; mi++) {
#pragma unroll
    for (int reg = 0; reg < 4; reg++) {
      int row = m0 + wm + mi * 16 + q * 4 + reg;
      float dv = EPI ? D[row] : 0.f;
#pragma unroll
      for (int ni = 0; ni < 4; ni++) {
        int col = n0 + wn + ni * 16 + r;
        size_t o = ((size_t)b * kM + row) * (size_t)kN + col;
        float v = acc[mi][ni][reg];
        if (EPI) {
          float y = v + dv * u[o];
          outf[o] = 0.5f * y * (1.f + erff(y * 0.70710678118654752f));
        } else {
          outh[o] = f2bf(v);
        }
      }
    }
  }
}

// ================================================================ GEMM2 (planar-B, k-transposed LDS)
// out[b][h][l] = sum_m A2[h][m] * xs[b][m][l], + D*u + GeLU.
// B LDS layout: off(m,l) = (l&15)*2 + (m>>3)*32 + (m&7)*128 + (l>>4)*1024;
// each 16B lane-window = {m fixed, 8 consecutive l} -> gl_lds-compatible.
// window decode (verified by hand, multiple cases):
//   lg=w>>10; rem=w&1023; im=(rem>>7)&7; qm=(rem>>5)&3; c=(rem>>4)&1;
//   m=qm*8+im; l=lg*16+c*8.
// Frag read: lane(q,r), elem i, col-block nj: byte = r*2 + q*32 + i*128 +
//   ((w&3)*4+nj)*1024  -> banks 8q+(r>>1): conflict-free, uniform immediates.

__device__ __forceinline__ int bwin_src(int wv) {
  int lg = wv >> 10, rem = wv & 1023;
  int im = (rem >> 7) & 7, qm = (rem >> 5) & 3, c = (rem >> 4) & 1;
  return (qm * 8 + im) * kN + lg * 16 + c * 8;  // element offset in xs tile
}

__global__ __launch_bounds__(512, 4) void k_gemm2t(
    const unsigned short* __restrict__ Ah, const unsigned short* __restrict__ Xs,
    float* __restrict__ out, const float* __restrict__ u,
    const float* __restrict__ D) {
  __shared__ __align__(16) unsigned char lds[49152];
  constexpr int BUF = 24576;
  constexpr int NKT = kK / 32;  // 32 K-tiles (k = m)

  int b = blockIdx.z;
  int m0 = blockIdx.y * 128, n0 = blockIdx.x * 256;
  int tid = threadIdx.x, w = tid >> 6;
  int q = (tid >> 4) & 3, r = tid & 15;
  int wm = (w >> 2) * 64, wn = (w & 3) * 64;
  int wmrb = (w >> 2) * 4;
  int lane_off = (r * 64 + q * 16) ^ ((r & 8) << 2);  // A-side read swizzle

  int d0 = tid << 4;
  int rowk = stage_src_off32(d0);          // A decode (rows = h)
  int bo1 = bwin_src(d0);                  // B window 1 (bytes 0..8191)
  int bo2 = bwin_src(8192 + d0);           // B window 2 (bytes 8192..16383)

  const unsigned short* pA = Ah + (size_t)m0 * kK;
  const unsigned short* pX = Xs + (size_t)b * ((size_t)kM * kN) + n0;

  f32x4 acc[4][4] = {};

#define STG2(KT, LB)                                                      \
  do {                                                                    \
    gl2lds16(pA + (KT) * 32 + rowk, lds + (LB) + d0);                     \
    gl2lds16(pX + (size_t)(KT) * 32 * kN + bo1, lds + (LB) + 8192 + d0);  \
    gl2lds16(pX + (size_t)(KT) * 32 * kN + bo2, lds + (LB) + 16384 + d0); \
  } while (0)

#define COMPUTE2(LB)                                                      \
  do {                                                                    \
    bf16x8 a[4], bb[4];                                                   \
    _Pragma("unroll")                                                     \
    for (int mi = 0; mi < 4; mi++)                                        \
      a[mi] = *(const bf16x8*)(lds + (LB) + ((wmrb + mi) << 10) + lane_off); \
    const unsigned char* bb_base =                                        \
        lds + (LB) + 8192 + r * 2 + q * 32 + ((w & 3) * 4) * 1024;        \
    _Pragma("unroll")                                                     \
    for (int nj = 0; nj < 4; nj++)                                        \
      _Pragma("unroll")                                                   \
      for (int i = 0; i < 8; i++)                                         \
        bb[nj][i] = *(const short*)(bb_base + nj * 1024 + i * 128);       \
    LGKM0;                                                                \
    __builtin_amdgcn_s_setprio(1);                                        \
    _Pragma("unroll")                                                     \
    for (int mi = 0; mi < 4; mi++)                                        \
      _Pragma("unroll")                                                   \
      for (int nj = 0; nj < 4; nj++)                                      \
        acc[mi][nj] = __builtin_amdgcn_mfma_f32_16x16x32_bf16(            \
            a[mi], bb[nj], acc[mi][nj], 0, 0, 0);                         \
    __builtin_amdgcn_s_setprio(0);                                        \
  } while (0)

  STG2(0, 0);
  wait_vm<0>();
  BAR;

  for (int it = 0; it < NKT / 2; ++it) {
    int kt = it * 2;
    if (kt + 1 < NKT) STG2(kt + 1, BUF);
    COMPUTE2(0);
    wait_vm<0>();
    BAR;
    if (kt + 2 < NKT) STG2(kt + 2, 0);
    COMPUTE2(BUF);
    wait_vm<0>();
    BAR;
  }
#undef STG2
#undef COMPUTE2

  // C/D layout: col = r, row = q*4 + reg; epilogue = D*u + exact GeLU
#pragma unroll
  for (int mi = 0; mi < 4; mi++) {
#pragma unroll
    for (int reg = 0; reg < 4; reg++) {
      int row = m0 + wm + mi * 16 + q * 4 + reg;
      float dv = D[row];
#pragma unroll
      for (int ni = 0; ni < 4; ni++) {
        int col = n0 + wn + ni * 16 + r;
        size_t o = ((size_t)b * kM + row) * (size_t)kN + col;
        float y = acc[mi][ni][reg] + dv * u[o];
        out[o] = 0.5f * y * (1.f + erff(y * 0.70710678118654752f));
      }
    }
  }
}

// ---------------------------------------------------------------- scan
// bf16 planar in (buh), fp32 internal, bf16 planar out (xsh).  [R13-proven]
__global__ __launch_bounds__(256) void k_scan(
    const unsigned short* __restrict__ buh, const float2* __restrict__ lbar,
    unsigned short* __restrict__ xsh) {
  int p = blockIdx.x & (kP - 1);
  int b = blockIdx.x >> 9;
  int tid = threadIdx.x, lane = tid & 63, w = tid >> 6;
  float2 lam = lbar[p];
  const unsigned short* sre = buh + ((size_t)b * kM + p) * (size_t)kN;
  const unsigned short* sim = sre + (size_t)kP * kN;

  float vr[16], vi[16];
  {
    const bf16x8* pr = (const bf16x8*)(sre + tid * 16);
    const bf16x8* pi = (const bf16x8*)(sim + tid * 16);
#pragma unroll
    for (int i = 0; i < 2; i++) {
      bf16x8 a = pr[i], c = pi[i];
#pragma unroll
      for (int j = 0; j < 8; j++) {
        vr[8 * i + j] = bf2f((unsigned short)a[j]);
        vi[8 * i + j] = bf2f((unsigned short)c[j]);
      }
    }
  }

  float xr = 0.f, xi = 0.f;
#pragma unroll
  for (int i = 0; i < 16; i++) {
    float nr2 = fmaf(lam.x, xr, fmaf(-lam.y, xi, vr[i]));
    float ni2 = fmaf(lam.x, xi, fmaf(lam.y, xr, vi[i]));
    xr = nr2; xi = ni2;
  }

  float Ar = lam.x, Ai = lam.y;
#pragma unroll
  for (int s = 0; s < 4; s++) {
    float tr = Ar * Ar - Ai * Ai, ti = 2.f * Ar * Ai;
    Ar = tr; Ai = ti;
  }
  float br = xr, bi = xi;

  for (int off = 1; off < 64; off <<= 1) {
    float pAr = __shfl_up(Ar, off), pAi = __shfl_up(Ai, off);
    float pbr = __shfl_up(br, off), pbi = __shfl_up(bi, off);
    if (lane >= off) {
      float nAr = Ar * pAr - Ai * pAi;
      float nAi = Ar * pAi + Ai * pAr;
      float nbr = Ar * pbr - Ai * pbi + br;
      float nbi = Ar * pbi + Ai * pbr + bi;
      Ar = nAr; Ai = nAi; br = nbr; bi = nbi;
    }
  }

  __shared__ float4 wtot[4];
  if (lane == 63) wtot[w] = make_float4(Ar, Ai, br, bi);
  __syncthreads();

  float eAr = __shfl_up(Ar, 1), eAi = __shfl_up(Ai, 1);
  float ebr = __shfl_up(br, 1), ebi = __shfl_up(bi, 1);
  if (lane == 0) { eAr = 1.f; eAi = 0.f; ebr = 0.f; ebi = 0.f; }

  float pAr = 1.f, pAi = 0.f, pbr = 0.f, pbi = 0.f;
  for (int j = 0; j < w; j++) {
    float4 t = wtot[j];
    float nAr = t.x * pAr - t.y * pAi;
    float nAi = t.x * pAi + t.y * pAr;
    float nbr = t.x * pbr - t.y * pbi + t.z;
    float nbi = t.x * pbi + t.y * pbr + t.w;
    pAr = nAr; pAi = nAi; pbr = nbr; pbi = nbi;
  }

  float initr = eAr * pbr - eAi * pbi + ebr;
  float initi = eAr * pbi + eAi * pbr + ebi;

  xr = initr; xi = initi;
  __align__(16) unsigned short hr[16], him[16];
#pragma unroll
  for (int i = 0; i < 16; i++) {
    float nr2 = fmaf(lam.x, xr, fmaf(-lam.y, xi, vr[i]));
    float ni2 = fmaf(lam.x, xi, fmaf(lam.y, xr, vi[i]));
    xr = nr2; xi = ni2;
    hr[i] = f2bf(nr2); him[i] = f2bf(ni2);
  }
  unsigned short* drh = xsh + ((size_t)b * kM + p) * (size_t)kN + tid * 16;
  unsigned short* dih = drh + (size_t)kP * kN;
  ((uint4*)drh)[0] = *(uint4*)&hr[0];
  ((uint4*)drh)[1] = *(uint4*)&hr[8];
  ((uint4*)dih)[0] = *(uint4*)&him[0];
  ((uint4*)dih)[1] = *(uint4*)&him[8];
}

// ================================================================ fp32 fallback
constexpr size_t OBBAR = 0;
constexpr size_t OLBAR = (size_t)kP * kH;
constexpr size_t OBU = OLBAR + 1024;

__global__ __launch_bounds__(256) void k_precomputeF(
    const float* __restrict__ Lre, const float* __restrict__ Lim,
    const float* __restrict__ B, const float* __restrict__ log_step,
    float2* __restrict__ ws) {
  int p = blockIdx.x;
  float lr = Lre[p], li = Lim[p];
  float step = expf(log_step[p]);
  float er = expf(lr * step);
  float sb, cb;
  sincosf(li * step, &sb, &cb);
  float lbr = er * cb, lbi = er * sb;
  float nr = lbr - 1.0f, ni = lbi;
  float inv = 1.0f / (lr * lr + li * li);
  float sr = (nr * lr + ni * li) * inv;
  float si = (ni * lr - nr * li) * inv;
  if (threadIdx.x == 0) ws[OLBAR + p] = make_float2(lbr, lbi);
  float2* Bbar = ws + OBBAR;
  const float* Brow = B + (size_t)p * kH * 2;
  for (int h = threadIdx.x; h < kH; h += 256) {
    float br = Brow[2 * h], bi = Brow[2 * h + 1];
    Bbar[(size_t)p * kH + h] = make_float2(sr * br - si * bi, sr * bi + si * br);
  }
}

__global__ __launch_bounds__(256) void k_gemm1F(
    const float2* __restrict__ ws_bbar, const float* __restrict__ u,
    float2* __restrict__ Bu) {
  __shared__ float2 As[16][64];
  __shared__ float Bs[16][64];
  int b = blockIdx.z, m0 = blockIdx.y * 64, n0 = blockIdx.x * 64;
  int tid = threadIdx.x, tn = tid & 15, tm = tid >> 4;
  const float* uB = u + (size_t)b * kH * kL;
  float2 acc[4][4];
#pragma unroll
  for (int i = 0; i < 4; i++)
#pragma unroll
    for (int j = 0; j < 4; j++) acc[i][j] = make_float2(0.f, 0.f);
  int ar = tid >> 2, ac = (tid & 3) * 4, bk = tid >> 4, bc = (tid & 15) * 4;
  for (int k0 = 0; k0 < kH; k0 += 16) {
    const float4* src = (const float4*)(ws_bbar + (size_t)(m0 + ar) * kH + k0 + ac);
    float4 v01 = src[0], v23 = src[1];
    As[ac + 0][ar] = make_float2(v01.x, v01.y);
    As[ac + 1][ar] = make_float2(v01.z, v01.w);
    As[ac + 2][ar] = make_float2(v23.x, v23.y);
    As[ac + 3][ar] = make_float2(v23.z, v23.w);
    float4 v = *(const float4*)(uB + (size_t)(k0 + bk) * kL + n0 + bc);
    *(float4*)&Bs[bk][bc] = v;
    __syncthreads();
#pragma unroll
    for (int kk = 0; kk < 16; ++kk) {
      const float4* arow = (const float4*)&As[kk][0];
      float4 a01 = arow[tm * 2 + 0], a23 = arow[tm * 2 + 1];
      float2 a[4] = {make_float2(a01.x, a01.y), make_float2(a01.z, a01.w),
                     make_float2(a23.x, a23.y), make_float2(a23.z, a23.w)};
      float4 bv = ((const float4*)&Bs[kk][0])[tn];
      float bbv[4] = {bv.x, bv.y, bv.z, bv.w};
#pragma unroll
      for (int mi = 0; mi < 4; mi++)
#pragma unroll
        for (int ni = 0; ni < 4; ni++) {
          acc[mi][ni].x = fmaf(a[mi].x, bbv[ni], acc[mi][ni].x);
          acc[mi][ni].y = fmaf(a[mi].y, bbv[ni], acc[mi][ni].y);
        }
    }
    __syncthreads();
  }
  float2* BuB = Bu + (size_t)b * kP * kL;
#pragma unroll
  for (int mi = 0; mi < 4; mi++) {
    int row = m0 + tm * 4 + mi;
    float2* dst = BuB + (size_t)row * kL + n0 + tn * 4;
    ((float4*)dst)[0] = make_float4(acc[mi][0].x, acc[mi][0].y, acc[mi][1].x, acc[mi][1].y);
    ((float4*)dst)[1] = make_float4(acc[mi][2].x, acc[mi][2].y, acc[mi][3].x, acc[mi][3].y);
  }
}

__global__ __launch_bounds__(256) void k_scanF(float2* __restrict__ Bu,
                                               const float2* __restrict__ Lbar) {
  int p = blockIdx.x & (kP - 1);
  int b = blockIdx.x >> 9;
  int tid = threadIdx.x, lane = tid & 63, w = tid >> 6;
  float2 lam = Lbar[p];
  float2* seq = Bu + ((size_t)b * kP + p) * kL;
  float2 v[16];
  const float4* src = (const float4*)(seq + tid * 16);
#pragma unroll
  for (int i = 0; i < 8; i++) {
    float4 t = src[i];
    v[2 * i] = make_float2(t.x, t.y);
    v[2 * i + 1] = make_float2(t.z, t.w);
  }
  float xr = 0.f, xi = 0.f;
#pragma unroll
  for (int i = 0; i < 16; i++) {
    float nr2 = fmaf(lam.x, xr, fmaf(-lam.y, xi, v[i].x));
    float ni2 = fmaf(lam.x, xi, fmaf(lam.y, xr, v[i].y));
    xr = nr2; xi = ni2;
  }
  float Ar = lam.x, Ai = lam.y;
#pragma unroll
  for (int s = 0; s < 4; s++) {
    float tr = Ar * Ar - Ai * Ai, ti = 2.f * Ar * Ai;
    Ar = tr; Ai = ti;
  }
  float br = xr, bi = xi;
  for (int off = 1; off < 64; off <<= 1) {
    float pAr = __shfl_up(Ar, off), pAi = __shfl_up(Ai, off);
    float pbr = __shfl_up(br, off), pbi = __shfl_up(bi, off);
    if (lane >= off) {
      float nAr = Ar * pAr - Ai * pAi, nAi = Ar * pAi + Ai * pAr;
      float nbr = Ar * pbr - Ai * pbi + br, nbi = Ar * pbi + Ai * pbr + bi;
      Ar = nAr; Ai = nAi; br = nbr; bi = nbi;
    }
  }
  __shared__ float4 wtot[4];
  if (lane == 63) wtot[w] = make_float4(Ar, Ai, br, bi);
  __syncthreads();
  float eAr = __shfl_up(Ar, 1), eAi = __shfl_up(Ai, 1);
  float ebr = __shfl_up(br, 1), ebi = __shfl_up(bi, 1);
  if (lane == 0) { eAr = 1.f; eAi = 0.f; ebr = 0.f; ebi = 0.f; }
  float pAr = 1.f, pAi = 0.f, pbr = 0.f, pbi = 0.f;
  for (int j = 0; j < w; j++) {
    float4 t = wtot[j];
    float nAr = t.x * pAr - t.y * pAi, nAi = t.x * pAi + t.y * pAr;
    float nbr = t.x * pbr - t.y * pbi + t.z, nbi = t.x * pbi + t.y * pbr + t.w;
    pAr = nAr; pAi = nAi; pbr = nbr; pbi = nbi;
  }
  float initr = eAr * pbr - eAi * pbi + ebr;
  float initi = eAr * pbi + eAi * pbr + ebi;
  xr = initr; xi = initi;
  float4* dst = (float4*)(seq + tid * 16);
#pragma unroll
  for (int i = 0; i < 8; i++) {
    float nr0 = fmaf(lam.x, xr, fmaf(-lam.y, xi, v[2 * i].x));
    float ni0 = fmaf(lam.x, xi, fmaf(lam.y, xr, v[2 * i].y));
    float nr1 = fmaf(lam.x, nr0, fmaf(-lam.y, ni0, v[2 * i + 1].x));
    float ni1 = fmaf(lam.x, ni0, fmaf(lam.y, nr0, v[2 * i + 1].y));
    dst[i] = make_float4(nr0, ni0, nr1, ni1);
    xr = nr1; xi = ni1;
  }
}

__global__ __launch_bounds__(256) void k_gemm2F(
    const float2* __restrict__ C, const float2* __restrict__ X,
    const float* __restrict__ u, const float* __restrict__ D,
    float* __restrict__ out) {
  __shared__ float2 As[16][64];
  __shared__ float2 Bs[16][64];
  int b = blockIdx.z, m0 = blockIdx.y * 64, n0 = blockIdx.x * 64;
  int tid = threadIdx.x, tn = tid & 15, tm = tid >> 4;
  const float2* Xb = X + (size_t)b * kP * kL;
  float acc[4][4];
#pragma unroll
  for (int i = 0; i < 4; i++)
#pragma unroll
    for (int j = 0; j < 4; j++) acc[i][j] = 0.f;
  int ar = tid >> 2, ac = (tid & 3) * 4, bk = tid >> 4, bc = (tid & 15) * 4;
  for (int k0 = 0; k0 < kP; k0 += 16) {
    const float4* src = (const float4*)(C + (size_t)(m0 + ar) * kP + k0 + ac);
    float4 v01 = src[0], v23 = src[1];
    As[ac + 0][ar] = make_float2(v01.x, v01.y);
    As[ac + 1][ar] = make_float2(v01.z, v01.w);
    As[ac + 2][ar] = make_float2(v23.x, v23.y);
    As[ac + 3][ar] = make_float2(v23.z, v23.w);
    const float4* srcb = (const float4*)(Xb + (size_t)(k0 + bk) * kL + n0 + bc);
    ((float4*)&Bs[bk][bc])[0] = srcb[0];
    ((float4*)&Bs[bk][bc])[1] = srcb[1];
    __syncthreads();
#pragma unroll
    for (int kk = 0; kk < 16; ++kk) {
      const float4* arow = (const float4*)&As[kk][0];
      float4 a01 = arow[tm * 2 + 0], a23 = arow[tm * 2 + 1];
      float2 a[4] = {make_float2(a01.x, a01.y), make_float2(a01.z, a01.w),
                     make_float2(a23.x, a23.y), make_float2(a23.z, a23.w)};
      const float4* brow = (const float4*)&Bs[kk][0];
      float4 b01 = brow[tn * 2 + 0], b23 = brow[tn * 2 + 1];
      float2 bbv[4] = {make_float2(b01.x, b01.y), make_float2(b01.z, b01.w),
                       make_float2(b23.x, b23.y), make_float2(b23.z, b23.w)};
#pragma unroll
      for (int mi = 0; mi < 4; mi++)
#pragma unroll
        for (int ni = 0; ni < 4; ni++) {
          acc[mi][ni] = fmaf(a[mi].x, bbv[ni].x, acc[mi][ni]);
          acc[mi][ni] = fmaf(-a[mi].y, bbv[ni].y, acc[mi][ni]);
        }
    }
    __syncthreads();
  }
#pragma unroll
  for (int mi = 0; mi < 4; mi++) {
    int h = m0 + tm * 4 + mi;
    float d = D[h];
    const float* urow = u + ((size_t)b * kH + h) * kL + n0 + tn * 4;
    float4 uv = *(const float4*)urow;
    float uu[4] = {uv.x, uv.y, uv.z, uv.w};
    float res[4];
#pragma unroll
    for (int ni = 0; ni < 4; ni++) {
      float y = 2.f * acc[mi][ni] + d * uu[ni];
      res[ni] = 0.5f * y * (1.f + erff(y * 0.70710678118654752f));
    }
    float* orow = out + ((size_t)b * kH + h) * kL + n0 + tn * 4;
    *(float4*)orow = make_float4(res[0], res[1], res[2], res[3]);
  }
}

// ---------------------------------------------------------------- launch
extern "C" void kernel_launch(void* const* d_in, const int* in_sizes, int n_in,
                              void* d_out, int out_size, void* d_ws, size_t ws_size,
                              hipStream_t stream) {
  const float* input_sequence = (const float*)d_in[0];
  const float* Lambda_re = (const float*)d_in[2];
  const float* Lambda_im = (const float*)d_in[3];
  const float* B = (const float*)d_in[4];
  const float* C = (const float*)d_in[5];
  const float* D = (const float*)d_in[6];
  const float* log_step = (const float*)d_in[7];
  float* out = (float*)d_out;

  if (ws_size >= MID_BYTES) {
    unsigned char* ws = (unsigned char*)d_ws;
    unsigned short* a1h = (unsigned short*)(ws + A1H_OFF);
    unsigned short* a2h = (unsigned short*)(ws + A2H_OFF);
    float2* lbar = (float2*)(ws + LBAR_B);
    unsigned short* th = (unsigned short*)(ws + TH_B);    // uT bf16
    unsigned short* buh = (unsigned short*)(ws + BU_B);   // Bu bf16 planar
    unsigned short* xsh = th;                             // xs bf16 planar (uT dead)

    // 1: prep + transpose1 (merged)
    k_prep_tr<<<dim3(4096 + kP + kH), 256, 0, stream>>>(
        Lambda_re, Lambda_im, B, log_step, C, ws, input_sequence, th);

    dim3 ggrid(kN / 256, kM / 128, kB);  // 16 x 8 x 4 = 512 blocks

    // 2: GEMM1 -> Bu bf16 planar
    k_gemm2p<false><<<ggrid, 512, 0, stream>>>(a1h, th, buh, nullptr, nullptr);
    // 3: scan (bf16 in, fp32 internal, bf16 out, planar)
    k_scan<<<dim3(kB * kP), 256, 0, stream>>>(buh, lbar, xsh);
    // 4: GEMM2 reads xs PLANAR (k-transposed LDS staging) + D*u + GeLU
    k_gemm2t<<<ggrid, 512, 0, stream>>>(a2h, xsh, out, input_sequence, D);
  } else {
    // fp32 fallback (round-1 path)
    float2* ws = (float2*)d_ws;
    float2* Bbar = ws + OBBAR;
    float2* Lbar = ws + OLBAR;
    float2* Bu = ws + OBU;
    k_precomputeF<<<dim3(kP), 256, 0, stream>>>(Lambda_re, Lambda_im, B, log_step, ws);
    k_gemm1F<<<dim3(kL / 64, kP / 64, kB), 256, 0, stream>>>(Bbar, input_sequence, Bu);
    k_scanF<<<dim3(kB * kP), 256, 0, stream>>>(Bu, Lbar);
    k_gemm2F<<<dim3(kL / 64, kH / 64, kB), 256, 0, stream>>>(
        (const float2*)C, (const float2*)Bu, input_sequence, D, out);
  }
}